// Round 21
// baseline (538.208 us; speedup 1.0000x reference)
//
#include <hip/hip_runtime.h>
#include <hip/hip_bf16.h>

#define BB 2
#define SS 2048
#define DD 2048
#define HH 16
#define DHH 128
#define MM 4096      // B*S
#define NN1 6144     // 3*D
#define NTILES (DD / 64)   // 32 K-tiles of 64

typedef __attribute__((ext_vector_type(8))) short bf16x8;
typedef __attribute__((ext_vector_type(4))) float f32x4;
typedef unsigned int u32;

static __device__ __forceinline__ float exp2_hw(float x) {
  return __builtin_amdgcn_exp2f(x);   // v_exp_f32
}

static __device__ __forceinline__ unsigned short f2bf(float f) {
  union { float f; u32 u; } v; v.f = f;
  return (unsigned short)((v.u + 0x7FFFu + ((v.u >> 16) & 1u)) >> 16);
}

static __device__ __forceinline__ u32 cvtpk_bf16(float lo, float hi) {
  u32 r;
  asm("v_cvt_pk_bf16_f32 %0, %1, %2" : "=v"(r) : "v"(lo), "v"(hi));
  return r;
}

static __device__ __forceinline__ void gload_lds16(const void* g, void* l) {
  __builtin_amdgcn_global_load_lds((const __attribute__((address_space(1))) u32*)g,
                                   (__attribute__((address_space(3))) u32*)l, 16, 0, 0);
}

// f32 -> bf16 elementwise, 4 elems/thread
__global__ __launch_bounds__(256) void k_cvt(const float* __restrict__ in,
                                             unsigned short* __restrict__ out) {
  int i = blockIdx.x * 256 + threadIdx.x;
  float4 v = ((const float4*)in)[i];
  ushort4 o;
  o.x = f2bf(v.x); o.y = f2bf(v.y); o.z = f2bf(v.z); o.w = f2bf(v.w);
  ((ushort4*)out)[i] = o;
}

// transpose f32 [R][C] -> bf16 [C][R], 32(col) x 64(row) tiles, ushort2 stores
__global__ __launch_bounds__(256) void k_transpose(const float* __restrict__ in,
                                                   unsigned short* __restrict__ out,
                                                   int R, int C) {
  __shared__ float t[64][33];
  int bx = blockIdx.x * 32, by = blockIdx.y * 64;
  int tx = threadIdx.x, ty = threadIdx.y;   // (32, 8)
  #pragma unroll
  for (int rr = 0; rr < 8; ++rr)
    t[ty + 8 * rr][tx] = in[(size_t)(by + ty + 8 * rr) * C + bx + tx];
  __syncthreads();
  #pragma unroll
  for (int ii = 0; ii < 4; ++ii) {
    int i = ty + 8 * ii;
    ushort2 w;
    w.x = f2bf(t[2 * tx][i]);
    w.y = f2bf(t[2 * tx + 1][i]);
    *(ushort2*)&out[(size_t)(bx + i) * R + by + 2 * tx] = w;
  }
}

// ======= GEMM1 core r21: 256x384 / BK=64 / 2Mx4N waves (128x96/wave) / dbuf 160KB =======
// r13 template, BN widened 192->384: MFMA/tile 3072cy vs LDS-read 1750cy (ratio 0.57),
// fixed per-tile barrier/drain amortized over 2x compute. Split-lgkm (14/0) unchanged.
__device__ __forceinline__ void gemm_core384(const char* __restrict__ Ag,
                                             const char* __restrict__ Bg,
                                             char* lds, f32x4 acc[8][6]) {
  const int tid = threadIdx.x;
  const int wave = tid >> 6, lane = tid & 63;
  const int g = lane >> 4, c = lane & 15;
  const int wm = wave >> 2, wn = wave & 3;

  // buf (80KB): [0,32K) A 256x64bf16, [32K,80K) B 384x64bf16. 128B rows,
  // swizzle cb ^= (row&7)<<4, linear gload dest + inverse-swizzled source.
  auto stage = [&](int buf, int kt) {
    char* base = lds + buf * 81920;
    #pragma unroll
    for (int q = 0; q < 4; ++q) {          // A: 4 loads/thread
      int off = q * 8192 + tid * 16;
      int row = off >> 7, cb = off & 127;
      gload_lds16(Ag + (size_t)row * 4096 + kt * 128 + (cb ^ ((row & 7) << 4)),
                  base + q * 8192 + wave * 1024);
    }
    #pragma unroll
    for (int q = 0; q < 6; ++q) {          // B: 6 loads/thread
      int off = q * 8192 + tid * 16;
      int row = off >> 7, cb = off & 127;
      gload_lds16(Bg + (size_t)row * 4096 + kt * 128 + (cb ^ ((row & 7) << 4)),
                  base + 32768 + q * 8192 + wave * 1024);
    }
  };

  stage(0, 0);
  asm volatile("s_waitcnt vmcnt(0)" ::: "memory");
  __builtin_amdgcn_sched_barrier(0);
  __builtin_amdgcn_s_barrier();

  for (int t = 0; t < NTILES; ++t) {
    const char* Ab = lds + (t & 1) * 81920;
    const char* Bb = Ab + 32768;
    bf16x8 af[8][2], bfv[6][2];
    // kk=0 batch (14 ds_read_b128) -- stays oldest for lgkmcnt(14)
    #pragma unroll
    for (int i = 0; i < 8; ++i) {
      int row = wm * 128 + i * 16 + c;
      af[i][0] = *(const bf16x8*)(Ab + row * 128 + ((g * 16) ^ ((row & 7) << 4)));
    }
    #pragma unroll
    for (int j = 0; j < 6; ++j) {
      int row = wn * 96 + j * 16 + c;
      bfv[j][0] = *(const bf16x8*)(Bb + row * 128 + ((g * 16) ^ ((row & 7) << 4)));
    }
    __builtin_amdgcn_sched_barrier(0);   // pin: kk0 batch precedes kk1 batch
    // kk=1 batch (14 ds_read_b128)
    #pragma unroll
    for (int i = 0; i < 8; ++i) {
      int row = wm * 128 + i * 16 + c;
      af[i][1] = *(const bf16x8*)(Ab + row * 128 + ((64 + g * 16) ^ ((row & 7) << 4)));
    }
    #pragma unroll
    for (int j = 0; j < 6; ++j) {
      int row = wn * 96 + j * 16 + c;
      bfv[j][1] = *(const bf16x8*)(Bb + row * 128 + ((64 + g * 16) ^ ((row & 7) << 4)));
    }
    if (t + 1 < NTILES) stage((t + 1) & 1, t + 1);
    asm volatile("s_waitcnt lgkmcnt(14)" ::: "memory");
    __builtin_amdgcn_sched_barrier(0);
    __builtin_amdgcn_s_setprio(1);
    #pragma unroll
    for (int i = 0; i < 8; ++i)
      #pragma unroll
      for (int j = 0; j < 6; ++j)
        acc[i][j] = __builtin_amdgcn_mfma_f32_16x16x32_bf16(af[i][0], bfv[j][0], acc[i][j], 0, 0, 0);
    __builtin_amdgcn_s_setprio(0);
    asm volatile("s_waitcnt lgkmcnt(0)" ::: "memory");
    __builtin_amdgcn_sched_barrier(0);
    __builtin_amdgcn_s_setprio(1);
    #pragma unroll
    for (int i = 0; i < 8; ++i)
      #pragma unroll
      for (int j = 0; j < 6; ++j)
        acc[i][j] = __builtin_amdgcn_mfma_f32_16x16x32_bf16(af[i][1], bfv[j][1], acc[i][j], 0, 0, 0);
    __builtin_amdgcn_s_setprio(0);
    if (t < NTILES - 1) {
      asm volatile("s_waitcnt vmcnt(0)" ::: "memory");
      __builtin_amdgcn_sched_barrier(0);
      __builtin_amdgcn_s_barrier();
    }
  }
}

// ========= r10-proven gemm2 core: 256x128 / BK=64 / split-lgkm / 144KB =========
__device__ __forceinline__ void gemm_core(const char* __restrict__ Ag,
                                          const char* __restrict__ Bg,
                                          char* Alds, char* Blds,
                                          f32x4 acc[4][4]) {
  const int tid = threadIdx.x;
  const int wave = tid >> 6, lane = tid & 63;
  const int g = lane >> 4, c = lane & 15;
  const int wm = wave >> 1, wn = wave & 1;

  auto stageA = [&](int buf, int kt) {
    #pragma unroll
    for (int q = 0; q < 4; ++q) {
      int off = q * 8192 + wave * 1024 + (lane << 4);
      int row = off >> 7, cb = off & 127;
      gload_lds16(Ag + (size_t)row * 4096 + kt * 128 + (cb ^ ((row & 7) << 4)),
                  Alds + buf * 32768 + q * 8192 + wave * 1024);
    }
  };
  auto stageB = [&](int buf, int kt) {
    #pragma unroll
    for (int q = 0; q < 2; ++q) {
      int off = q * 8192 + wave * 1024 + (lane << 4);
      int row = off >> 7, cb = off & 127;
      gload_lds16(Bg + (size_t)row * 4096 + kt * 128 + (cb ^ ((row & 7) << 4)),
                  Blds + buf * 16384 + q * 8192 + wave * 1024);
    }
  };

  stageA(0, 0); stageB(0, 0);
  stageA(1, 1); stageB(1, 1);
  asm volatile("s_waitcnt vmcnt(6)" ::: "memory");
  __builtin_amdgcn_sched_barrier(0);
  __builtin_amdgcn_s_barrier();

  for (int t = 0; t < NTILES; ++t) {
    const int buf = t % 3;
    const char* Ab = Alds + buf * 32768;
    const char* Bb = Blds + buf * 16384;
    bf16x8 af[4][2], bfv[4][2];
    #pragma unroll
    for (int i = 0; i < 4; ++i) {
      int row = wm * 64 + i * 16 + c;
      af[i][0] = *(const bf16x8*)(Ab + row * 128 + ((g * 16) ^ ((row & 7) << 4)));
    }
    #pragma unroll
    for (int j = 0; j < 4; ++j) {
      int row = wn * 64 + j * 16 + c;
      bfv[j][0] = *(const bf16x8*)(Bb + row * 128 + ((g * 16) ^ ((row & 7) << 4)));
    }
    __builtin_amdgcn_sched_barrier(0);
    #pragma unroll
    for (int i = 0; i < 4; ++i) {
      int row = wm * 64 + i * 16 + c;
      af[i][1] = *(const bf16x8*)(Ab + row * 128 + ((64 + g * 16) ^ ((row & 7) << 4)));
    }
    #pragma unroll
    for (int j = 0; j < 4; ++j) {
      int row = wn * 64 + j * 16 + c;
      bfv[j][1] = *(const bf16x8*)(Bb + row * 128 + ((64 + g * 16) ^ ((row & 7) << 4)));
    }
    if (t + 2 < NTILES) {
      int nb = buf + 2; if (nb >= 3) nb -= 3;
      stageA(nb, t + 2);
      stageB(nb, t + 2);
    }
    asm volatile("s_waitcnt lgkmcnt(8)" ::: "memory");
    __builtin_amdgcn_sched_barrier(0);
    __builtin_amdgcn_s_setprio(1);
    #pragma unroll
    for (int i = 0; i < 4; ++i)
      #pragma unroll
      for (int j = 0; j < 4; ++j)
        acc[i][j] = __builtin_amdgcn_mfma_f32_16x16x32_bf16(af[i][0], bfv[j][0], acc[i][j], 0, 0, 0);
    __builtin_amdgcn_s_setprio(0);
    asm volatile("s_waitcnt lgkmcnt(0)" ::: "memory");
    __builtin_amdgcn_sched_barrier(0);
    __builtin_amdgcn_s_setprio(1);
    #pragma unroll
    for (int i = 0; i < 4; ++i)
      #pragma unroll
      for (int j = 0; j < 4; ++j)
        acc[i][j] = __builtin_amdgcn_mfma_f32_16x16x32_bf16(af[i][1], bfv[j][1], acc[i][j], 0, 0, 0);
    __builtin_amdgcn_s_setprio(0);
    if (t < NTILES - 1) {
      if (t + 2 < NTILES) { asm volatile("s_waitcnt vmcnt(6)" ::: "memory"); }
      else                { asm volatile("s_waitcnt vmcnt(0)" ::: "memory"); }
      __builtin_amdgcn_sched_barrier(0);
      __builtin_amdgcn_s_barrier();
    }
  }
}

// ---- GEMM1: x[M][K] * Wqkv^T[N][K] + bqkv -> scatter Q/K/Vt (Q pre-scaled) ----
__global__ __launch_bounds__(512, 1) void k_gemm1(const unsigned short* __restrict__ A,
                                                  const unsigned short* __restrict__ Bt,
                                                  const float* __restrict__ bias,
                                                  unsigned short* __restrict__ Qb,
                                                  unsigned short* __restrict__ Kb,
                                                  unsigned short* __restrict__ Vt) {
  __shared__ __align__(16) char lds[163840];
  // grid 256 = 16mt x 16nt (1 block/CU, no tail); per XCD a 4m x 8n rect
  const int x = blockIdx.x & 7, k = blockIdx.x >> 3;
  const int mt = (x & 3) * 4 + (k & 3), nt = (x >> 2) * 8 + (k >> 2);
  const int m0 = mt * 256, n0 = nt * 384;
  f32x4 acc[8][6] = {};
  gemm_core384((const char*)A + (size_t)m0 * 4096,
               (const char*)Bt + (size_t)n0 * 4096,
               lds, acc);
  const int lane = threadIdx.x & 63, wave = threadIdx.x >> 6;
  const int g = lane >> 4, c = lane & 15;
  const int wm = wave >> 2, wn = wave & 3;
  const float qsc = 0.12751879523263566f;  // (1/sqrt(128)) * log2(e): folded into Q
  #pragma unroll
  for (int i = 0; i < 8; ++i) {
    int rowb = m0 + wm * 128 + i * 16 + g * 4;
    int bb = rowb >> 11, s = rowb & 2047;
    #pragma unroll
    for (int j = 0; j < 6; ++j) {
      int gcol = n0 + wn * 96 + j * 16 + c;
      int which = gcol >> 11;               // per-column: 384-tiles cross Q/K/V bounds
      int head = (gcol >> 7) & 15, dh = gcol & 127;
      float bv = bias[gcol];
      if (which == 2) {
        ushort4 p;
        p.x = f2bf(acc[i][j][0] + bv);
        p.y = f2bf(acc[i][j][1] + bv);
        p.z = f2bf(acc[i][j][2] + bv);
        p.w = f2bf(acc[i][j][3] + bv);
        *(ushort4*)(Vt + ((size_t)(bb * HH + head) * DHH + dh) * SS + s) = p;
      } else {
        float v0 = acc[i][j][0] + bv, v1 = acc[i][j][1] + bv;
        float v2 = acc[i][j][2] + bv, v3 = acc[i][j][3] + bv;
        if (which == 0) { v0 *= qsc; v1 *= qsc; v2 *= qsc; v3 *= qsc; }
        unsigned short* dst = (which == 0 ? Qb : Kb) + ((size_t)(bb * HH + head) * SS + s) * DHH + dh;
        dst[0]       = f2bf(v0);
        dst[DHH]     = f2bf(v1);
        dst[2 * DHH] = f2bf(v2);
        dst[3 * DHH] = f2bf(v3);
      }
    }
  }
}

// ---- GEMM2: O[M][D] * Wproj^T[D][D] + bproj -> f32 out (r10 core) ----
__global__ __launch_bounds__(512, 1) void k_gemm2(const unsigned short* __restrict__ A,
                                                  const unsigned short* __restrict__ Bt,
                                                  const float* __restrict__ bias,
                                                  float* __restrict__ out) {
  __shared__ __align__(16) char lds[147456];
  const int n0 = blockIdx.x * 128, m0 = blockIdx.y * 256;
  f32x4 acc[4][4] = {};
  gemm_core((const char*)A + (size_t)m0 * 4096,
            (const char*)Bt + (size_t)n0 * 4096,
            lds, lds + 98304, acc);
  const int lane = threadIdx.x & 63, wave = threadIdx.x >> 6;
  const int g = lane >> 4, c = lane & 15;
  const int wm = wave >> 1, wn = wave & 1;
  #pragma unroll
  for (int i = 0; i < 4; ++i) {
    int rowb = m0 + wm * 64 + i * 16 + g * 4;
    #pragma unroll
    for (int j = 0; j < 4; ++j) {
      int gcol = n0 + wn * 64 + j * 16 + c;
      float bv = bias[gcol];
      #pragma unroll
      for (int r = 0; r < 4; ++r)
        out[(size_t)(rowb + r) * DD + gcol] = acc[i][j][r] + bv;
    }
  }
}

// ---- flash attention v7 (r17-proven): XCD-local bh mapping, no-max softmax,
//      deferred lsum reduction, cvt_pk P-packing ----
__global__ __launch_bounds__(256, 2) void k_attn(const unsigned short* __restrict__ Qb,
                                                 const unsigned short* __restrict__ Kb,
                                                 const unsigned short* __restrict__ Vt,
                                                 unsigned short* __restrict__ O) {
  __shared__ __align__(16) unsigned short Kt[2][64 * 128];
  __shared__ __align__(16) unsigned short Vs[2][128 * 64];
  __shared__ __align__(16) unsigned short Pl[4][32 * 64];
  const int L = blockIdx.x;
  const int xcd = L & 7, slot = L >> 3;
  const int bh = (xcd << 2) | (slot >> 4);
  const int sloc = slot & 15;
  const int qtl = (slot & 32) ? (15 - sloc) : sloc;
  const int b = bh >> 4, h = bh & 15;
  const int tid = threadIdx.x, wave = tid >> 6, lane = tid & 63;
  const int g = lane >> 4, c = lane & 15;
  const int q0w = qtl * 128 + wave * 32;
  const unsigned short* Qp = Qb + (size_t)bh * SS * DHH;
  const unsigned short* Kp = Kb + (size_t)bh * SS * DHH;
  const unsigned short* Vp = Vt + (size_t)bh * DHH * SS;

  bf16x8 qf[2][4];
  #pragma unroll
  for (int m = 0; m < 2; ++m)
    #pragma unroll
    for (int ks = 0; ks < 4; ++ks)
      qf[m][ks] = *(const bf16x8*)(Qp + (size_t)(q0w + m * 16 + c) * DHH + ks * 32 + g * 8);

  f32x4 acc[2][8] = {};
  float lsum[2] = {0.f, 0.f};

  auto stage = [&](int buf, int kv0) {
    #pragma unroll
    for (int r = 0; r < 4; ++r) {
      int base = r * 4096 + wave * 1024;
      int off = base + (lane << 4);
      { int row = off >> 8; int cb = (off & 255) ^ ((row & 7) << 4);
        gload_lds16((const char*)Kp + (size_t)(kv0 + row) * 256 + cb,
                    (char*)Kt[buf] + base); }
      { int row = off >> 7; int cb = (off & 127) ^ ((row & 7) << 4);
        gload_lds16((const char*)Vp + (size_t)row * (SS * 2) + (size_t)kv0 * 2 + cb,
                    (char*)Vs[buf] + base); }
    }
  };

  const int ntiles = 2 * qtl + 2;
  stage(0, 0);
  __syncthreads();

  for (int t = 0; t < ntiles; ++t) {
    const int cur = t & 1;
    const int kv0 = t * 64;
    if (t + 1 < ntiles) stage(cur ^ 1, kv0 + 64);
    if (kv0 <= q0w + 31) {
      const unsigned short* K_ = Kt[cur];
      const unsigned short* V_ = Vs[cur];
      f32x4 sa[2][4] = {};
      __builtin_amdgcn_s_setprio(1);
      #pragma unroll
      for (int nb = 0; nb < 4; ++nb) {
        const int rk = nb * 16 + c;
        const int swz = (rk & 7) << 4;
        #pragma unroll
        for (int ks = 0; ks < 4; ++ks) {
          bf16x8 kf = *(const bf16x8*)((const char*)K_ + rk * 256 + ((ks * 64 + g * 16) ^ swz));
          sa[0][nb] = __builtin_amdgcn_mfma_f32_16x16x32_bf16(kf, qf[0][ks], sa[0][nb], 0, 0, 0);
          sa[1][nb] = __builtin_amdgcn_mfma_f32_16x16x32_bf16(kf, qf[1][ks], sa[1][nb], 0, 0, 0);
        }
      }
      __builtin_amdgcn_s_setprio(0);
      const bool diag = (kv0 + 63 > q0w);
      #pragma unroll
      for (int m = 0; m < 2; ++m) {
        const int q = q0w + m * 16 + c;
        float p[4][4];
        float rs = 0.f;
        if (diag) {
          #pragma unroll
          for (int nb = 0; nb < 4; ++nb)
            #pragma unroll
            for (int r = 0; r < 4; ++r) {
              float s = (kv0 + nb * 16 + g * 4 + r > q) ? -1e30f : sa[m][nb][r];
              p[nb][r] = exp2_hw(s);
              rs += p[nb][r];
            }
        } else {
          #pragma unroll
          for (int nb = 0; nb < 4; ++nb)
            #pragma unroll
            for (int r = 0; r < 4; ++r) {
              p[nb][r] = exp2_hw(sa[m][nb][r]);
              rs += p[nb][r];
            }
        }
        lsum[m] += rs;
        const int rowp = m * 16 + c;
        const int swzp = (rowp & 7) << 4;
        #pragma unroll
        for (int nb = 0; nb < 4; ++nb)
          #pragma unroll
          for (int i2 = 0; i2 < 2; ++i2) {
            u32 w = cvtpk_bf16(p[nb][2 * i2], p[nb][2 * i2 + 1]);
            *(u32*)((char*)Pl[wave] + rowp * 128 + (((nb * 16 + g * 4 + 2 * i2) * 2) ^ swzp)) = w;
          }
      }
      asm volatile("s_waitcnt lgkmcnt(0)" ::: "memory");
      __builtin_amdgcn_sched_barrier(0);
      bf16x8 pf[2][2];
      #pragma unroll
      for (int m = 0; m < 2; ++m)
        #pragma unroll
        for (int c2 = 0; c2 < 2; ++c2) {
          int rowp = m * 16 + c;
          pf[m][c2] = *(const bf16x8*)((const char*)Pl[wave] + rowp * 128 +
                                       ((c2 * 64 + g * 16) ^ ((rowp & 7) << 4)));
        }
      __builtin_amdgcn_s_setprio(1);
      #pragma unroll
      for (int nf = 0; nf < 8; ++nf) {
        const int rv = nf * 16 + c;
        const int swzv = (rv & 7) << 4;
        #pragma unroll
        for (int c2 = 0; c2 < 2; ++c2) {
          bf16x8 vf = *(const bf16x8*)((const char*)V_ + rv * 128 + ((c2 * 64 + g * 16) ^ swzv));
          acc[0][nf] = __builtin_amdgcn_mfma_f32_16x16x32_bf16(pf[0][c2], vf, acc[0][nf], 0, 0, 0);
          acc[1][nf] = __builtin_amdgcn_mfma_f32_16x16x32_bf16(pf[1][c2], vf, acc[1][nf], 0, 0, 0);
        }
      }
      __builtin_amdgcn_s_setprio(0);
    }
    __syncthreads();
  }

  #pragma unroll
  for (int m = 0; m < 2; ++m) {
    lsum[m] += __shfl_xor(lsum[m], 16, 64);
    lsum[m] += __shfl_xor(lsum[m], 32, 64);
  }

  unsigned short* Op = O + (size_t)b * SS * DD + (size_t)h * DHH;
  #pragma unroll
  for (int m = 0; m < 2; ++m) {
    float inv = 1.0f / lsum[m];
    float invr[4];
    #pragma unroll
    for (int r = 0; r < 4; ++r)
      invr[r] = __shfl(inv, 20 * g + r, 64);
    #pragma unroll
    for (int nf = 0; nf < 8; ++nf)
      #pragma unroll
      for (int r = 0; r < 4; ++r) {
        int q = q0w + m * 16 + g * 4 + r;
        Op[(size_t)q * DD + nf * 16 + c] = f2bf(acc[m][nf][r] * invr[r]);
      }
  }
}

extern "C" void kernel_launch(void* const* d_in, const int* in_sizes, int n_in,
                              void* d_out, int out_size, void* d_ws, size_t ws_size,
                              hipStream_t stream) {
  const float* x     = (const float*)d_in[0];
  const float* Wqkv  = (const float*)d_in[1];
  const float* bqkv  = (const float*)d_in[2];
  const float* Wproj = (const float*)d_in[3];
  const float* bproj = (const float*)d_in[4];
  float* out = (float*)d_out;

  char* ws = (char*)d_ws;
  unsigned short* xb  = (unsigned short*)ws; ws += (size_t)MM * DD * 2;
  unsigned short* w1t = (unsigned short*)ws; ws += (size_t)NN1 * DD * 2;
  unsigned short* w2t = (unsigned short*)ws; ws += (size_t)DD * DD * 2;
  unsigned short* Qb  = (unsigned short*)ws; ws += (size_t)BB * HH * SS * DHH * 2;
  unsigned short* Kb  = (unsigned short*)ws; ws += (size_t)BB * HH * SS * DHH * 2;
  unsigned short* Vt  = (unsigned short*)ws; ws += (size_t)BB * HH * SS * DHH * 2;
  unsigned short* Ob  = (unsigned short*)ws; ws += (size_t)MM * DD * 2;

  k_cvt<<<dim3((MM * DD) / 1024), 256, 0, stream>>>(x, xb);
  k_transpose<<<dim3(NN1 / 32, DD / 64), dim3(32, 8), 0, stream>>>(Wqkv, w1t, DD, NN1);
  k_transpose<<<dim3(DD / 32, DD / 64), dim3(32, 8), 0, stream>>>(Wproj, w2t, DD, DD);
  k_gemm1<<<dim3(256), 512, 0, stream>>>(xb, w1t, bqkv, Qb, Kb, Vt);
  k_attn<<<dim3(512), 256, 0, stream>>>(Qb, Kb, Vt, Ob);
  k_gemm2<<<dim3(DD / 128, MM / 256), 512, 0, stream>>>(Ob, w2t, bproj, out);
}

// Round 22
// 230.905 us; speedup vs baseline: 2.3309x; 2.3309x over previous
//
#include <hip/hip_runtime.h>
#include <hip/hip_bf16.h>

#define BB 2
#define SS 2048
#define DD 2048
#define HH 16
#define DHH 128
#define MM 4096      // B*S
#define NN1 6144     // 3*D
#define NTILES (DD / 64)   // 32 K-tiles of 64

typedef __attribute__((ext_vector_type(8))) short bf16x8;
typedef __attribute__((ext_vector_type(4))) float f32x4;
typedef unsigned int u32;

static __device__ __forceinline__ float exp2_hw(float x) {
  return __builtin_amdgcn_exp2f(x);   // v_exp_f32
}

static __device__ __forceinline__ unsigned short f2bf(float f) {
  union { float f; u32 u; } v; v.f = f;
  return (unsigned short)((v.u + 0x7FFFu + ((v.u >> 16) & 1u)) >> 16);
}

static __device__ __forceinline__ u32 cvtpk_bf16(float lo, float hi) {
  u32 r;
  asm("v_cvt_pk_bf16_f32 %0, %1, %2" : "=v"(r) : "v"(lo), "v"(hi));
  return r;
}

static __device__ __forceinline__ void gload_lds16(const void* g, void* l) {
  __builtin_amdgcn_global_load_lds((const __attribute__((address_space(1))) u32*)g,
                                   (__attribute__((address_space(3))) u32*)l, 16, 0, 0);
}

// f32 -> bf16 elementwise, 4 elems/thread
__global__ __launch_bounds__(256) void k_cvt(const float* __restrict__ in,
                                             unsigned short* __restrict__ out) {
  int i = blockIdx.x * 256 + threadIdx.x;
  float4 v = ((const float4*)in)[i];
  ushort4 o;
  o.x = f2bf(v.x); o.y = f2bf(v.y); o.z = f2bf(v.z); o.w = f2bf(v.w);
  ((ushort4*)out)[i] = o;
}

// transpose f32 [R][C] -> bf16 [C][R], 32(col) x 64(row) tiles, ushort2 stores
// (128B fully-coalesced writes; LDS read stride 66 words = 2-way aliasing = free)
__global__ __launch_bounds__(256) void k_transpose(const float* __restrict__ in,
                                                   unsigned short* __restrict__ out,
                                                   int R, int C) {
  __shared__ float t[64][33];
  int bx = blockIdx.x * 32, by = blockIdx.y * 64;
  int tx = threadIdx.x, ty = threadIdx.y;   // (32, 8)
  #pragma unroll
  for (int rr = 0; rr < 8; ++rr)
    t[ty + 8 * rr][tx] = in[(size_t)(by + ty + 8 * rr) * C + bx + tx];
  __syncthreads();
  #pragma unroll
  for (int ii = 0; ii < 4; ++ii) {
    int i = ty + 8 * ii;
    ushort2 w;
    w.x = f2bf(t[2 * tx][i]);
    w.y = f2bf(t[2 * tx + 1][i]);
    *(ushort2*)&out[(size_t)(bx + i) * R + by + 2 * tx] = w;
  }
}

// ======= GEMM1 core (r13/r17-proven): 256x192 / BK=64 / 2Mx4N waves / dbuf 112KB =======
__device__ __forceinline__ void gemm_core192(const char* __restrict__ Ag,
                                             const char* __restrict__ Bg,
                                             char* lds, f32x4 acc[8][3]) {
  const int tid = threadIdx.x;
  const int wave = tid >> 6, lane = tid & 63;
  const int g = lane >> 4, c = lane & 15;
  const int wm = wave >> 2, wn = wave & 3;

  auto stage = [&](int buf, int kt) {
    char* base = lds + buf * 57344;
    #pragma unroll
    for (int q = 0; q < 4; ++q) {          // A: 4 loads/thread
      int off = q * 8192 + tid * 16;
      int row = off >> 7, cb = off & 127;
      gload_lds16(Ag + (size_t)row * 4096 + kt * 128 + (cb ^ ((row & 7) << 4)),
                  base + q * 8192 + wave * 1024);
    }
    #pragma unroll
    for (int q = 0; q < 3; ++q) {          // B: 3 loads/thread
      int off = q * 8192 + tid * 16;
      int row = off >> 7, cb = off & 127;
      gload_lds16(Bg + (size_t)row * 4096 + kt * 128 + (cb ^ ((row & 7) << 4)),
                  base + 32768 + q * 8192 + wave * 1024);
    }
  };

  stage(0, 0);
  asm volatile("s_waitcnt vmcnt(0)" ::: "memory");
  __builtin_amdgcn_sched_barrier(0);
  __builtin_amdgcn_s_barrier();

  for (int t = 0; t < NTILES; ++t) {
    const char* Ab = lds + (t & 1) * 57344;
    const char* Bb = Ab + 32768;
    bf16x8 af[8][2], bfv[3][2];
    #pragma unroll
    for (int i = 0; i < 8; ++i) {
      int row = wm * 128 + i * 16 + c;
      af[i][0] = *(const bf16x8*)(Ab + row * 128 + ((g * 16) ^ ((row & 7) << 4)));
    }
    #pragma unroll
    for (int j = 0; j < 3; ++j) {
      int row = wn * 48 + j * 16 + c;
      bfv[j][0] = *(const bf16x8*)(Bb + row * 128 + ((g * 16) ^ ((row & 7) << 4)));
    }
    __builtin_amdgcn_sched_barrier(0);
    #pragma unroll
    for (int i = 0; i < 8; ++i) {
      int row = wm * 128 + i * 16 + c;
      af[i][1] = *(const bf16x8*)(Ab + row * 128 + ((64 + g * 16) ^ ((row & 7) << 4)));
    }
    #pragma unroll
    for (int j = 0; j < 3; ++j) {
      int row = wn * 48 + j * 16 + c;
      bfv[j][1] = *(const bf16x8*)(Bb + row * 128 + ((64 + g * 16) ^ ((row & 7) << 4)));
    }
    if (t + 1 < NTILES) stage((t + 1) & 1, t + 1);
    asm volatile("s_waitcnt lgkmcnt(11)" ::: "memory");
    __builtin_amdgcn_sched_barrier(0);
    __builtin_amdgcn_s_setprio(1);
    #pragma unroll
    for (int i = 0; i < 8; ++i)
      #pragma unroll
      for (int j = 0; j < 3; ++j)
        acc[i][j] = __builtin_amdgcn_mfma_f32_16x16x32_bf16(af[i][0], bfv[j][0], acc[i][j], 0, 0, 0);
    __builtin_amdgcn_s_setprio(0);
    asm volatile("s_waitcnt lgkmcnt(0)" ::: "memory");
    __builtin_amdgcn_sched_barrier(0);
    __builtin_amdgcn_s_setprio(1);
    #pragma unroll
    for (int i = 0; i < 8; ++i)
      #pragma unroll
      for (int j = 0; j < 3; ++j)
        acc[i][j] = __builtin_amdgcn_mfma_f32_16x16x32_bf16(af[i][1], bfv[j][1], acc[i][j], 0, 0, 0);
    __builtin_amdgcn_s_setprio(0);
    if (t < NTILES - 1) {
      asm volatile("s_waitcnt vmcnt(0)" ::: "memory");
      __builtin_amdgcn_sched_barrier(0);
      __builtin_amdgcn_s_barrier();
    }
  }
}

// ========= r10-proven gemm2 core: 256x128 / BK=64 / split-lgkm / 144KB =========
__device__ __forceinline__ void gemm_core(const char* __restrict__ Ag,
                                          const char* __restrict__ Bg,
                                          char* Alds, char* Blds,
                                          f32x4 acc[4][4]) {
  const int tid = threadIdx.x;
  const int wave = tid >> 6, lane = tid & 63;
  const int g = lane >> 4, c = lane & 15;
  const int wm = wave >> 1, wn = wave & 1;

  auto stageA = [&](int buf, int kt) {
    #pragma unroll
    for (int q = 0; q < 4; ++q) {
      int off = q * 8192 + wave * 1024 + (lane << 4);
      int row = off >> 7, cb = off & 127;
      gload_lds16(Ag + (size_t)row * 4096 + kt * 128 + (cb ^ ((row & 7) << 4)),
                  Alds + buf * 32768 + q * 8192 + wave * 1024);
    }
  };
  auto stageB = [&](int buf, int kt) {
    #pragma unroll
    for (int q = 0; q < 2; ++q) {
      int off = q * 8192 + wave * 1024 + (lane << 4);
      int row = off >> 7, cb = off & 127;
      gload_lds16(Bg + (size_t)row * 4096 + kt * 128 + (cb ^ ((row & 7) << 4)),
                  Blds + buf * 16384 + q * 8192 + wave * 1024);
    }
  };

  stageA(0, 0); stageB(0, 0);
  stageA(1, 1); stageB(1, 1);
  asm volatile("s_waitcnt vmcnt(6)" ::: "memory");
  __builtin_amdgcn_sched_barrier(0);
  __builtin_amdgcn_s_barrier();

  for (int t = 0; t < NTILES; ++t) {
    const int buf = t % 3;
    const char* Ab = Alds + buf * 32768;
    const char* Bb = Blds + buf * 16384;
    bf16x8 af[4][2], bfv[4][2];
    #pragma unroll
    for (int i = 0; i < 4; ++i) {
      int row = wm * 64 + i * 16 + c;
      af[i][0] = *(const bf16x8*)(Ab + row * 128 + ((g * 16) ^ ((row & 7) << 4)));
    }
    #pragma unroll
    for (int j = 0; j < 4; ++j) {
      int row = wn * 64 + j * 16 + c;
      bfv[j][0] = *(const bf16x8*)(Bb + row * 128 + ((g * 16) ^ ((row & 7) << 4)));
    }
    __builtin_amdgcn_sched_barrier(0);
    #pragma unroll
    for (int i = 0; i < 4; ++i) {
      int row = wm * 64 + i * 16 + c;
      af[i][1] = *(const bf16x8*)(Ab + row * 128 + ((64 + g * 16) ^ ((row & 7) << 4)));
    }
    #pragma unroll
    for (int j = 0; j < 4; ++j) {
      int row = wn * 64 + j * 16 + c;
      bfv[j][1] = *(const bf16x8*)(Bb + row * 128 + ((64 + g * 16) ^ ((row & 7) << 4)));
    }
    if (t + 2 < NTILES) {
      int nb = buf + 2; if (nb >= 3) nb -= 3;
      stageA(nb, t + 2);
      stageB(nb, t + 2);
    }
    asm volatile("s_waitcnt lgkmcnt(8)" ::: "memory");
    __builtin_amdgcn_sched_barrier(0);
    __builtin_amdgcn_s_setprio(1);
    #pragma unroll
    for (int i = 0; i < 4; ++i)
      #pragma unroll
      for (int j = 0; j < 4; ++j)
        acc[i][j] = __builtin_amdgcn_mfma_f32_16x16x32_bf16(af[i][0], bfv[j][0], acc[i][j], 0, 0, 0);
    __builtin_amdgcn_s_setprio(0);
    asm volatile("s_waitcnt lgkmcnt(0)" ::: "memory");
    __builtin_amdgcn_sched_barrier(0);
    __builtin_amdgcn_s_setprio(1);
    #pragma unroll
    for (int i = 0; i < 4; ++i)
      #pragma unroll
      for (int j = 0; j < 4; ++j)
        acc[i][j] = __builtin_amdgcn_mfma_f32_16x16x32_bf16(af[i][1], bfv[j][1], acc[i][j], 0, 0, 0);
    __builtin_amdgcn_s_setprio(0);
    if (t < NTILES - 1) {
      if (t + 2 < NTILES) { asm volatile("s_waitcnt vmcnt(6)" ::: "memory"); }
      else                { asm volatile("s_waitcnt vmcnt(0)" ::: "memory"); }
      __builtin_amdgcn_sched_barrier(0);
      __builtin_amdgcn_s_barrier();
    }
  }
}

// ---- GEMM1: x[M][K] * Wqkv^T[N][K] + bqkv -> scatter Q/K/Vt (Q pre-scaled) ----
__global__ __launch_bounds__(512, 1) void k_gemm1(const unsigned short* __restrict__ A,
                                                  const unsigned short* __restrict__ Bt,
                                                  const float* __restrict__ bias,
                                                  unsigned short* __restrict__ Qb,
                                                  unsigned short* __restrict__ Kb,
                                                  unsigned short* __restrict__ Vt) {
  __shared__ __align__(16) char lds[114688];
  const int x = blockIdx.x & 7, k = blockIdx.x >> 3;
  const int mt = (x & 1) * 8 + (k & 7), nt = (x >> 1) * 8 + (k >> 3);
  const int m0 = mt * 256, n0 = nt * 192;
  f32x4 acc[8][3] = {};
  gemm_core192((const char*)A + (size_t)m0 * 4096,
               (const char*)Bt + (size_t)n0 * 4096,
               lds, acc);
  const int lane = threadIdx.x & 63, wave = threadIdx.x >> 6;
  const int g = lane >> 4, c = lane & 15;
  const int wm = wave >> 2, wn = wave & 3;
  const float qsc = 0.12751879523263566f;  // (1/sqrt(128)) * log2(e): folded into Q
  #pragma unroll
  for (int i = 0; i < 8; ++i) {
    int rowb = m0 + wm * 128 + i * 16 + g * 4;
    int bb = rowb >> 11, s = rowb & 2047;
    #pragma unroll
    for (int j = 0; j < 3; ++j) {
      int gcol = n0 + wn * 48 + j * 16 + c;
      int which = gcol >> 11;
      int head = (gcol >> 7) & 15, dh = gcol & 127;
      float bv = bias[gcol];
      if (which == 2) {
        ushort4 p;
        p.x = f2bf(acc[i][j][0] + bv);
        p.y = f2bf(acc[i][j][1] + bv);
        p.z = f2bf(acc[i][j][2] + bv);
        p.w = f2bf(acc[i][j][3] + bv);
        *(ushort4*)(Vt + ((size_t)(bb * HH + head) * DHH + dh) * SS + s) = p;
      } else {
        float v0 = acc[i][j][0] + bv, v1 = acc[i][j][1] + bv;
        float v2 = acc[i][j][2] + bv, v3 = acc[i][j][3] + bv;
        if (which == 0) { v0 *= qsc; v1 *= qsc; v2 *= qsc; v3 *= qsc; }
        unsigned short* dst = (which == 0 ? Qb : Kb) + ((size_t)(bb * HH + head) * SS + s) * DHH + dh;
        dst[0]       = f2bf(v0);
        dst[DHH]     = f2bf(v1);
        dst[2 * DHH] = f2bf(v2);
        dst[3 * DHH] = f2bf(v3);
      }
    }
  }
}

// ---- GEMM2: O[M][D] * Wproj^T[D][D] + bproj -> f32 out (r10 core) ----
__global__ __launch_bounds__(512, 1) void k_gemm2(const unsigned short* __restrict__ A,
                                                  const unsigned short* __restrict__ Bt,
                                                  const float* __restrict__ bias,
                                                  float* __restrict__ out) {
  __shared__ __align__(16) char lds[147456];
  const int n0 = blockIdx.x * 128, m0 = blockIdx.y * 256;
  f32x4 acc[4][4] = {};
  gemm_core((const char*)A + (size_t)m0 * 4096,
            (const char*)Bt + (size_t)n0 * 4096,
            lds, lds + 98304, acc);
  const int lane = threadIdx.x & 63, wave = threadIdx.x >> 6;
  const int g = lane >> 4, c = lane & 15;
  const int wm = wave >> 1, wn = wave & 1;
  #pragma unroll
  for (int i = 0; i < 4; ++i) {
    int rowb = m0 + wm * 64 + i * 16 + g * 4;
    #pragma unroll
    for (int j = 0; j < 4; ++j) {
      int gcol = n0 + wn * 64 + j * 16 + c;
      float bv = bias[gcol];
      #pragma unroll
      for (int r = 0; r < 4; ++r)
        out[(size_t)(rowb + r) * DD + gcol] = acc[i][j][r] + bv;
    }
  }
}

// ---- flash attention v7 (r17-proven): XCD-local bh mapping, no-max softmax,
//      deferred lsum reduction, cvt_pk P-packing ----
__global__ __launch_bounds__(256, 2) void k_attn(const unsigned short* __restrict__ Qb,
                                                 const unsigned short* __restrict__ Kb,
                                                 const unsigned short* __restrict__ Vt,
                                                 unsigned short* __restrict__ O) {
  __shared__ __align__(16) unsigned short Kt[2][64 * 128];
  __shared__ __align__(16) unsigned short Vs[2][128 * 64];
  __shared__ __align__(16) unsigned short Pl[4][32 * 64];
  const int L = blockIdx.x;
  const int xcd = L & 7, slot = L >> 3;
  const int bh = (xcd << 2) | (slot >> 4);
  const int sloc = slot & 15;
  const int qtl = (slot & 32) ? (15 - sloc) : sloc;
  const int b = bh >> 4, h = bh & 15;
  const int tid = threadIdx.x, wave = tid >> 6, lane = tid & 63;
  const int g = lane >> 4, c = lane & 15;
  const int q0w = qtl * 128 + wave * 32;
  const unsigned short* Qp = Qb + (size_t)bh * SS * DHH;
  const unsigned short* Kp = Kb + (size_t)bh * SS * DHH;
  const unsigned short* Vp = Vt + (size_t)bh * DHH * SS;

  bf16x8 qf[2][4];
  #pragma unroll
  for (int m = 0; m < 2; ++m)
    #pragma unroll
    for (int ks = 0; ks < 4; ++ks)
      qf[m][ks] = *(const bf16x8*)(Qp + (size_t)(q0w + m * 16 + c) * DHH + ks * 32 + g * 8);

  f32x4 acc[2][8] = {};
  float lsum[2] = {0.f, 0.f};

  auto stage = [&](int buf, int kv0) {
    #pragma unroll
    for (int r = 0; r < 4; ++r) {
      int base = r * 4096 + wave * 1024;
      int off = base + (lane << 4);
      { int row = off >> 8; int cb = (off & 255) ^ ((row & 7) << 4);
        gload_lds16((const char*)Kp + (size_t)(kv0 + row) * 256 + cb,
                    (char*)Kt[buf] + base); }
      { int row = off >> 7; int cb = (off & 127) ^ ((row & 7) << 4);
        gload_lds16((const char*)Vp + (size_t)row * (SS * 2) + (size_t)kv0 * 2 + cb,
                    (char*)Vs[buf] + base); }
    }
  };

  const int ntiles = 2 * qtl + 2;
  stage(0, 0);
  __syncthreads();

  for (int t = 0; t < ntiles; ++t) {
    const int cur = t & 1;
    const int kv0 = t * 64;
    if (t + 1 < ntiles) stage(cur ^ 1, kv0 + 64);
    if (kv0 <= q0w + 31) {
      const unsigned short* K_ = Kt[cur];
      const unsigned short* V_ = Vs[cur];
      f32x4 sa[2][4] = {};
      __builtin_amdgcn_s_setprio(1);
      #pragma unroll
      for (int nb = 0; nb < 4; ++nb) {
        const int rk = nb * 16 + c;
        const int swz = (rk & 7) << 4;
        #pragma unroll
        for (int ks = 0; ks < 4; ++ks) {
          bf16x8 kf = *(const bf16x8*)((const char*)K_ + rk * 256 + ((ks * 64 + g * 16) ^ swz));
          sa[0][nb] = __builtin_amdgcn_mfma_f32_16x16x32_bf16(kf, qf[0][ks], sa[0][nb], 0, 0, 0);
          sa[1][nb] = __builtin_amdgcn_mfma_f32_16x16x32_bf16(kf, qf[1][ks], sa[1][nb], 0, 0, 0);
        }
      }
      __builtin_amdgcn_s_setprio(0);
      const bool diag = (kv0 + 63 > q0w);
      #pragma unroll
      for (int m = 0; m < 2; ++m) {
        const int q = q0w + m * 16 + c;
        float p[4][4];
        float rs = 0.f;
        if (diag) {
          #pragma unroll
          for (int nb = 0; nb < 4; ++nb)
            #pragma unroll
            for (int r = 0; r < 4; ++r) {
              float s = (kv0 + nb * 16 + g * 4 + r > q) ? -1e30f : sa[m][nb][r];
              p[nb][r] = exp2_hw(s);
              rs += p[nb][r];
            }
        } else {
          #pragma unroll
          for (int nb = 0; nb < 4; ++nb)
            #pragma unroll
            for (int r = 0; r < 4; ++r) {
              p[nb][r] = exp2_hw(sa[m][nb][r]);
              rs += p[nb][r];
            }
        }
        lsum[m] += rs;
        const int rowp = m * 16 + c;
        const int swzp = (rowp & 7) << 4;
        #pragma unroll
        for (int nb = 0; nb < 4; ++nb)
          #pragma unroll
          for (int i2 = 0; i2 < 2; ++i2) {
            u32 w = cvtpk_bf16(p[nb][2 * i2], p[nb][2 * i2 + 1]);
            *(u32*)((char*)Pl[wave] + rowp * 128 + (((nb * 16 + g * 4 + 2 * i2) * 2) ^ swzp)) = w;
          }
      }
      asm volatile("s_waitcnt lgkmcnt(0)" ::: "memory");
      __builtin_amdgcn_sched_barrier(0);
      bf16x8 pf[2][2];
      #pragma unroll
      for (int m = 0; m < 2; ++m)
        #pragma unroll
        for (int c2 = 0; c2 < 2; ++c2) {
          int rowp = m * 16 + c;
          pf[m][c2] = *(const bf16x8*)((const char*)Pl[wave] + rowp * 128 +
                                       ((c2 * 64 + g * 16) ^ ((rowp & 7) << 4)));
        }
      __builtin_amdgcn_s_setprio(1);
      #pragma unroll
      for (int nf = 0; nf < 8; ++nf) {
        const int rv = nf * 16 + c;
        const int swzv = (rv & 7) << 4;
        #pragma unroll
        for (int c2 = 0; c2 < 2; ++c2) {
          bf16x8 vf = *(const bf16x8*)((const char*)V_ + rv * 128 + ((c2 * 64 + g * 16) ^ swzv));
          acc[0][nf] = __builtin_amdgcn_mfma_f32_16x16x32_bf16(pf[0][c2], vf, acc[0][nf], 0, 0, 0);
          acc[1][nf] = __builtin_amdgcn_mfma_f32_16x16x32_bf16(pf[1][c2], vf, acc[1][nf], 0, 0, 0);
        }
      }
      __builtin_amdgcn_s_setprio(0);
    }
    __syncthreads();
  }

  #pragma unroll
  for (int m = 0; m < 2; ++m) {
    lsum[m] += __shfl_xor(lsum[m], 16, 64);
    lsum[m] += __shfl_xor(lsum[m], 32, 64);
  }

  unsigned short* Op = O + (size_t)b * SS * DD + (size_t)h * DHH;
  #pragma unroll
  for (int m = 0; m < 2; ++m) {
    float inv = 1.0f / lsum[m];
    float invr[4];
    #pragma unroll
    for (int r = 0; r < 4; ++r)
      invr[r] = __shfl(inv, 20 * g + r, 64);
    #pragma unroll
    for (int nf = 0; nf < 8; ++nf)
      #pragma unroll
      for (int r = 0; r < 4; ++r) {
        int q = q0w + m * 16 + g * 4 + r;
        Op[(size_t)q * DD + nf * 16 + c] = f2bf(acc[m][nf][r] * invr[r]);
      }
  }
}

extern "C" void kernel_launch(void* const* d_in, const int* in_sizes, int n_in,
                              void* d_out, int out_size, void* d_ws, size_t ws_size,
                              hipStream_t stream) {
  const float* x     = (const float*)d_in[0];
  const float* Wqkv  = (const float*)d_in[1];
  const float* bqkv  = (const float*)d_in[2];
  const float* Wproj = (const float*)d_in[3];
  const float* bproj = (const float*)d_in[4];
  float* out = (float*)d_out;

  char* ws = (char*)d_ws;
  unsigned short* xb  = (unsigned short*)ws; ws += (size_t)MM * DD * 2;
  unsigned short* w1t = (unsigned short*)ws; ws += (size_t)NN1 * DD * 2;
  unsigned short* w2t = (unsigned short*)ws; ws += (size_t)DD * DD * 2;
  unsigned short* Qb  = (unsigned short*)ws; ws += (size_t)BB * HH * SS * DHH * 2;
  unsigned short* Kb  = (unsigned short*)ws; ws += (size_t)BB * HH * SS * DHH * 2;
  unsigned short* Vt  = (unsigned short*)ws; ws += (size_t)BB * HH * SS * DHH * 2;
  unsigned short* Ob  = (unsigned short*)ws; ws += (size_t)MM * DD * 2;

  k_cvt<<<dim3((MM * DD) / 1024), 256, 0, stream>>>(x, xb);
  k_transpose<<<dim3(NN1 / 32, DD / 64), dim3(32, 8), 0, stream>>>(Wqkv, w1t, DD, NN1);
  k_transpose<<<dim3(DD / 32, DD / 64), dim3(32, 8), 0, stream>>>(Wproj, w2t, DD, DD);
  k_gemm1<<<dim3(512), 512, 0, stream>>>(xb, w1t, bqkv, Qb, Kb, Vt);
  k_attn<<<dim3(512), 256, 0, stream>>>(Qb, Kb, Vt, Ob);
  k_gemm2<<<dim3(DD / 128, MM / 256), 512, 0, stream>>>(Ob, w2t, bproj, out);
}

// Round 23
// 227.757 us; speedup vs baseline: 2.3631x; 1.0138x over previous
//
#include <hip/hip_runtime.h>
#include <hip/hip_bf16.h>

#define BB 2
#define SS 2048
#define DD 2048
#define HH 16
#define DHH 128
#define MM 4096      // B*S
#define NN1 6144     // 3*D
#define NTILES (DD / 64)   // 32 K-tiles of 64

typedef __attribute__((ext_vector_type(8))) short bf16x8;
typedef __attribute__((ext_vector_type(4))) float f32x4;
typedef unsigned int u32;

static __device__ __forceinline__ float exp2_hw(float x) {
  return __builtin_amdgcn_exp2f(x);   // v_exp_f32
}

static __device__ __forceinline__ unsigned short f2bf(float f) {
  union { float f; u32 u; } v; v.f = f;
  return (unsigned short)((v.u + 0x7FFFu + ((v.u >> 16) & 1u)) >> 16);
}

static __device__ __forceinline__ u32 cvtpk_bf16(float lo, float hi) {
  u32 r;
  asm("v_cvt_pk_bf16_f32 %0, %1, %2" : "=v"(r) : "v"(lo), "v"(hi));
  return r;
}

static __device__ __forceinline__ void gload_lds16(const void* g, void* l) {
  __builtin_amdgcn_global_load_lds((const __attribute__((address_space(1))) u32*)g,
                                   (__attribute__((address_space(3))) u32*)l, 16, 0, 0);
}

// ---- fused prep: cvt x->bf16 + transpose Wqkv + transpose Wproj in ONE dispatch.
//      blocks [0,8192): cvt (float4/ushort4); [8192,14336): Wqkv^T; [14336,16384): Wproj^T.
//      Branch is block-uniform; transposes use 32col x 64row tiles, ushort2 stores. ----
__global__ __launch_bounds__(256) void k_prep(const float* __restrict__ x,
                                              unsigned short* __restrict__ xb,
                                              const float* __restrict__ Wqkv,
                                              unsigned short* __restrict__ w1t,
                                              const float* __restrict__ Wproj,
                                              unsigned short* __restrict__ w2t) {
  const int bid = blockIdx.x, tid = threadIdx.x;
  if (bid < 8192) {                      // ---- cvt: x (f32) -> xb (bf16) ----
    int i = bid * 256 + tid;
    float4 v = ((const float4*)x)[i];
    ushort4 o;
    o.x = f2bf(v.x); o.y = f2bf(v.y); o.z = f2bf(v.z); o.w = f2bf(v.w);
    ((ushort4*)xb)[i] = o;
    return;                              // block-uniform exit (no sync hazard)
  }
  __shared__ float t[64][33];
  const float* in; unsigned short* out;
  int R, C, bx, by;
  if (bid < 14336) {                     // ---- Wqkv [DD][NN1] -> w1t [NN1][DD] ----
    int idx = bid - 8192;                // 192 x 32 tiles
    in = Wqkv; out = w1t; R = DD; C = NN1;
    bx = (idx % 192) * 32; by = (idx / 192) * 64;
  } else {                               // ---- Wproj [DD][DD] -> w2t [DD][DD] ----
    int idx = bid - 14336;               // 64 x 32 tiles
    in = Wproj; out = w2t; R = DD; C = DD;
    bx = (idx % 64) * 32; by = (idx / 64) * 64;
  }
  const int tx = tid & 31, ty = tid >> 5;
  #pragma unroll
  for (int rr = 0; rr < 8; ++rr)
    t[ty + 8 * rr][tx] = in[(size_t)(by + ty + 8 * rr) * C + bx + tx];
  __syncthreads();
  #pragma unroll
  for (int ii = 0; ii < 4; ++ii) {
    int i = ty + 8 * ii;
    ushort2 w;
    w.x = f2bf(t[2 * tx][i]);
    w.y = f2bf(t[2 * tx + 1][i]);
    *(ushort2*)&out[(size_t)(bx + i) * R + by + 2 * tx] = w;
  }
}

// ======= GEMM1 core (r13/r17-proven): 256x192 / BK=64 / 2Mx4N waves / dbuf 112KB =======
__device__ __forceinline__ void gemm_core192(const char* __restrict__ Ag,
                                             const char* __restrict__ Bg,
                                             char* lds, f32x4 acc[8][3]) {
  const int tid = threadIdx.x;
  const int wave = tid >> 6, lane = tid & 63;
  const int g = lane >> 4, c = lane & 15;
  const int wm = wave >> 2, wn = wave & 3;

  auto stage = [&](int buf, int kt) {
    char* base = lds + buf * 57344;
    #pragma unroll
    for (int q = 0; q < 4; ++q) {          // A: 4 loads/thread
      int off = q * 8192 + tid * 16;
      int row = off >> 7, cb = off & 127;
      gload_lds16(Ag + (size_t)row * 4096 + kt * 128 + (cb ^ ((row & 7) << 4)),
                  base + q * 8192 + wave * 1024);
    }
    #pragma unroll
    for (int q = 0; q < 3; ++q) {          // B: 3 loads/thread
      int off = q * 8192 + tid * 16;
      int row = off >> 7, cb = off & 127;
      gload_lds16(Bg + (size_t)row * 4096 + kt * 128 + (cb ^ ((row & 7) << 4)),
                  base + 32768 + q * 8192 + wave * 1024);
    }
  };

  stage(0, 0);
  asm volatile("s_waitcnt vmcnt(0)" ::: "memory");
  __builtin_amdgcn_sched_barrier(0);
  __builtin_amdgcn_s_barrier();

  for (int t = 0; t < NTILES; ++t) {
    const char* Ab = lds + (t & 1) * 57344;
    const char* Bb = Ab + 32768;
    bf16x8 af[8][2], bfv[3][2];
    #pragma unroll
    for (int i = 0; i < 8; ++i) {
      int row = wm * 128 + i * 16 + c;
      af[i][0] = *(const bf16x8*)(Ab + row * 128 + ((g * 16) ^ ((row & 7) << 4)));
    }
    #pragma unroll
    for (int j = 0; j < 3; ++j) {
      int row = wn * 48 + j * 16 + c;
      bfv[j][0] = *(const bf16x8*)(Bb + row * 128 + ((g * 16) ^ ((row & 7) << 4)));
    }
    __builtin_amdgcn_sched_barrier(0);
    #pragma unroll
    for (int i = 0; i < 8; ++i) {
      int row = wm * 128 + i * 16 + c;
      af[i][1] = *(const bf16x8*)(Ab + row * 128 + ((64 + g * 16) ^ ((row & 7) << 4)));
    }
    #pragma unroll
    for (int j = 0; j < 3; ++j) {
      int row = wn * 48 + j * 16 + c;
      bfv[j][1] = *(const bf16x8*)(Bb + row * 128 + ((64 + g * 16) ^ ((row & 7) << 4)));
    }
    if (t + 1 < NTILES) stage((t + 1) & 1, t + 1);
    asm volatile("s_waitcnt lgkmcnt(11)" ::: "memory");
    __builtin_amdgcn_sched_barrier(0);
    __builtin_amdgcn_s_setprio(1);
    #pragma unroll
    for (int i = 0; i < 8; ++i)
      #pragma unroll
      for (int j = 0; j < 3; ++j)
        acc[i][j] = __builtin_amdgcn_mfma_f32_16x16x32_bf16(af[i][0], bfv[j][0], acc[i][j], 0, 0, 0);
    __builtin_amdgcn_s_setprio(0);
    asm volatile("s_waitcnt lgkmcnt(0)" ::: "memory");
    __builtin_amdgcn_sched_barrier(0);
    __builtin_amdgcn_s_setprio(1);
    #pragma unroll
    for (int i = 0; i < 8; ++i)
      #pragma unroll
      for (int j = 0; j < 3; ++j)
        acc[i][j] = __builtin_amdgcn_mfma_f32_16x16x32_bf16(af[i][1], bfv[j][1], acc[i][j], 0, 0, 0);
    __builtin_amdgcn_s_setprio(0);
    if (t < NTILES - 1) {
      asm volatile("s_waitcnt vmcnt(0)" ::: "memory");
      __builtin_amdgcn_sched_barrier(0);
      __builtin_amdgcn_s_barrier();
    }
  }
}

// ========= r10-proven gemm2 core: 256x128 / BK=64 / split-lgkm / 144KB =========
__device__ __forceinline__ void gemm_core(const char* __restrict__ Ag,
                                          const char* __restrict__ Bg,
                                          char* Alds, char* Blds,
                                          f32x4 acc[4][4]) {
  const int tid = threadIdx.x;
  const int wave = tid >> 6, lane = tid & 63;
  const int g = lane >> 4, c = lane & 15;
  const int wm = wave >> 1, wn = wave & 1;

  auto stageA = [&](int buf, int kt) {
    #pragma unroll
    for (int q = 0; q < 4; ++q) {
      int off = q * 8192 + wave * 1024 + (lane << 4);
      int row = off >> 7, cb = off & 127;
      gload_lds16(Ag + (size_t)row * 4096 + kt * 128 + (cb ^ ((row & 7) << 4)),
                  Alds + buf * 32768 + q * 8192 + wave * 1024);
    }
  };
  auto stageB = [&](int buf, int kt) {
    #pragma unroll
    for (int q = 0; q < 2; ++q) {
      int off = q * 8192 + wave * 1024 + (lane << 4);
      int row = off >> 7, cb = off & 127;
      gload_lds16(Bg + (size_t)row * 4096 + kt * 128 + (cb ^ ((row & 7) << 4)),
                  Blds + buf * 16384 + q * 8192 + wave * 1024);
    }
  };

  stageA(0, 0); stageB(0, 0);
  stageA(1, 1); stageB(1, 1);
  asm volatile("s_waitcnt vmcnt(6)" ::: "memory");
  __builtin_amdgcn_sched_barrier(0);
  __builtin_amdgcn_s_barrier();

  for (int t = 0; t < NTILES; ++t) {
    const int buf = t % 3;
    const char* Ab = Alds + buf * 32768;
    const char* Bb = Blds + buf * 16384;
    bf16x8 af[4][2], bfv[4][2];
    #pragma unroll
    for (int i = 0; i < 4; ++i) {
      int row = wm * 64 + i * 16 + c;
      af[i][0] = *(const bf16x8*)(Ab + row * 128 + ((g * 16) ^ ((row & 7) << 4)));
    }
    #pragma unroll
    for (int j = 0; j < 4; ++j) {
      int row = wn * 64 + j * 16 + c;
      bfv[j][0] = *(const bf16x8*)(Bb + row * 128 + ((g * 16) ^ ((row & 7) << 4)));
    }
    __builtin_amdgcn_sched_barrier(0);
    #pragma unroll
    for (int i = 0; i < 4; ++i) {
      int row = wm * 64 + i * 16 + c;
      af[i][1] = *(const bf16x8*)(Ab + row * 128 + ((64 + g * 16) ^ ((row & 7) << 4)));
    }
    #pragma unroll
    for (int j = 0; j < 4; ++j) {
      int row = wn * 64 + j * 16 + c;
      bfv[j][1] = *(const bf16x8*)(Bb + row * 128 + ((64 + g * 16) ^ ((row & 7) << 4)));
    }
    if (t + 2 < NTILES) {
      int nb = buf + 2; if (nb >= 3) nb -= 3;
      stageA(nb, t + 2);
      stageB(nb, t + 2);
    }
    asm volatile("s_waitcnt lgkmcnt(8)" ::: "memory");
    __builtin_amdgcn_sched_barrier(0);
    __builtin_amdgcn_s_setprio(1);
    #pragma unroll
    for (int i = 0; i < 4; ++i)
      #pragma unroll
      for (int j = 0; j < 4; ++j)
        acc[i][j] = __builtin_amdgcn_mfma_f32_16x16x32_bf16(af[i][0], bfv[j][0], acc[i][j], 0, 0, 0);
    __builtin_amdgcn_s_setprio(0);
    asm volatile("s_waitcnt lgkmcnt(0)" ::: "memory");
    __builtin_amdgcn_sched_barrier(0);
    __builtin_amdgcn_s_setprio(1);
    #pragma unroll
    for (int i = 0; i < 4; ++i)
      #pragma unroll
      for (int j = 0; j < 4; ++j)
        acc[i][j] = __builtin_amdgcn_mfma_f32_16x16x32_bf16(af[i][1], bfv[j][1], acc[i][j], 0, 0, 0);
    __builtin_amdgcn_s_setprio(0);
    if (t < NTILES - 1) {
      if (t + 2 < NTILES) { asm volatile("s_waitcnt vmcnt(6)" ::: "memory"); }
      else                { asm volatile("s_waitcnt vmcnt(0)" ::: "memory"); }
      __builtin_amdgcn_sched_barrier(0);
      __builtin_amdgcn_s_barrier();
    }
  }
}

// ---- GEMM1: x[M][K] * Wqkv^T[N][K] + bqkv -> scatter Q/K/Vt (Q pre-scaled) ----
__global__ __launch_bounds__(512, 1) void k_gemm1(const unsigned short* __restrict__ A,
                                                  const unsigned short* __restrict__ Bt,
                                                  const float* __restrict__ bias,
                                                  unsigned short* __restrict__ Qb,
                                                  unsigned short* __restrict__ Kb,
                                                  unsigned short* __restrict__ Vt) {
  __shared__ __align__(16) char lds[114688];
  const int x = blockIdx.x & 7, k = blockIdx.x >> 3;
  const int mt = (x & 1) * 8 + (k & 7), nt = (x >> 1) * 8 + (k >> 3);
  const int m0 = mt * 256, n0 = nt * 192;
  f32x4 acc[8][3] = {};
  gemm_core192((const char*)A + (size_t)m0 * 4096,
               (const char*)Bt + (size_t)n0 * 4096,
               lds, acc);
  const int lane = threadIdx.x & 63, wave = threadIdx.x >> 6;
  const int g = lane >> 4, c = lane & 15;
  const int wm = wave >> 2, wn = wave & 3;
  const float qsc = 0.12751879523263566f;  // (1/sqrt(128)) * log2(e): folded into Q
  #pragma unroll
  for (int i = 0; i < 8; ++i) {
    int rowb = m0 + wm * 128 + i * 16 + g * 4;
    int bb = rowb >> 11, s = rowb & 2047;
    #pragma unroll
    for (int j = 0; j < 3; ++j) {
      int gcol = n0 + wn * 48 + j * 16 + c;
      int which = gcol >> 11;
      int head = (gcol >> 7) & 15, dh = gcol & 127;
      float bv = bias[gcol];
      if (which == 2) {
        ushort4 p;
        p.x = f2bf(acc[i][j][0] + bv);
        p.y = f2bf(acc[i][j][1] + bv);
        p.z = f2bf(acc[i][j][2] + bv);
        p.w = f2bf(acc[i][j][3] + bv);
        *(ushort4*)(Vt + ((size_t)(bb * HH + head) * DHH + dh) * SS + s) = p;
      } else {
        float v0 = acc[i][j][0] + bv, v1 = acc[i][j][1] + bv;
        float v2 = acc[i][j][2] + bv, v3 = acc[i][j][3] + bv;
        if (which == 0) { v0 *= qsc; v1 *= qsc; v2 *= qsc; v3 *= qsc; }
        unsigned short* dst = (which == 0 ? Qb : Kb) + ((size_t)(bb * HH + head) * SS + s) * DHH + dh;
        dst[0]       = f2bf(v0);
        dst[DHH]     = f2bf(v1);
        dst[2 * DHH] = f2bf(v2);
        dst[3 * DHH] = f2bf(v3);
      }
    }
  }
}

// ---- GEMM2: O[M][D] * Wproj^T[D][D] + bproj -> f32 out (r10 core) ----
__global__ __launch_bounds__(512, 1) void k_gemm2(const unsigned short* __restrict__ A,
                                                  const unsigned short* __restrict__ Bt,
                                                  const float* __restrict__ bias,
                                                  float* __restrict__ out) {
  __shared__ __align__(16) char lds[147456];
  const int n0 = blockIdx.x * 128, m0 = blockIdx.y * 256;
  f32x4 acc[4][4] = {};
  gemm_core((const char*)A + (size_t)m0 * 4096,
            (const char*)Bt + (size_t)n0 * 4096,
            lds, lds + 98304, acc);
  const int lane = threadIdx.x & 63, wave = threadIdx.x >> 6;
  const int g = lane >> 4, c = lane & 15;
  const int wm = wave >> 1, wn = wave & 1;
  #pragma unroll
  for (int i = 0; i < 4; ++i) {
    int rowb = m0 + wm * 64 + i * 16 + g * 4;
    #pragma unroll
    for (int j = 0; j < 4; ++j) {
      int gcol = n0 + wn * 64 + j * 16 + c;
      float bv = bias[gcol];
      #pragma unroll
      for (int r = 0; r < 4; ++r)
        out[(size_t)(rowb + r) * DD + gcol] = acc[i][j][r] + bv;
    }
  }
}

// ---- flash attention v7 (r17-proven): XCD-local bh mapping, no-max softmax,
//      deferred lsum reduction, cvt_pk P-packing ----
__global__ __launch_bounds__(256, 2) void k_attn(const unsigned short* __restrict__ Qb,
                                                 const unsigned short* __restrict__ Kb,
                                                 const unsigned short* __restrict__ Vt,
                                                 unsigned short* __restrict__ O) {
  __shared__ __align__(16) unsigned short Kt[2][64 * 128];
  __shared__ __align__(16) unsigned short Vs[2][128 * 64];
  __shared__ __align__(16) unsigned short Pl[4][32 * 64];
  const int L = blockIdx.x;
  const int xcd = L & 7, slot = L >> 3;
  const int bh = (xcd << 2) | (slot >> 4);
  const int sloc = slot & 15;
  const int qtl = (slot & 32) ? (15 - sloc) : sloc;
  const int b = bh >> 4, h = bh & 15;
  const int tid = threadIdx.x, wave = tid >> 6, lane = tid & 63;
  const int g = lane >> 4, c = lane & 15;
  const int q0w = qtl * 128 + wave * 32;
  const unsigned short* Qp = Qb + (size_t)bh * SS * DHH;
  const unsigned short* Kp = Kb + (size_t)bh * SS * DHH;
  const unsigned short* Vp = Vt + (size_t)bh * DHH * SS;

  bf16x8 qf[2][4];
  #pragma unroll
  for (int m = 0; m < 2; ++m)
    #pragma unroll
    for (int ks = 0; ks < 4; ++ks)
      qf[m][ks] = *(const bf16x8*)(Qp + (size_t)(q0w + m * 16 + c) * DHH + ks * 32 + g * 8);

  f32x4 acc[2][8] = {};
  float lsum[2] = {0.f, 0.f};

  auto stage = [&](int buf, int kv0) {
    #pragma unroll
    for (int r = 0; r < 4; ++r) {
      int base = r * 4096 + wave * 1024;
      int off = base + (lane << 4);
      { int row = off >> 8; int cb = (off & 255) ^ ((row & 7) << 4);
        gload_lds16((const char*)Kp + (size_t)(kv0 + row) * 256 + cb,
                    (char*)Kt[buf] + base); }
      { int row = off >> 7; int cb = (off & 127) ^ ((row & 7) << 4);
        gload_lds16((const char*)Vp + (size_t)row * (SS * 2) + (size_t)kv0 * 2 + cb,
                    (char*)Vs[buf] + base); }
    }
  };

  const int ntiles = 2 * qtl + 2;
  stage(0, 0);
  __syncthreads();

  for (int t = 0; t < ntiles; ++t) {
    const int cur = t & 1;
    const int kv0 = t * 64;
    if (t + 1 < ntiles) stage(cur ^ 1, kv0 + 64);
    if (kv0 <= q0w + 31) {
      const unsigned short* K_ = Kt[cur];
      const unsigned short* V_ = Vs[cur];
      f32x4 sa[2][4] = {};
      __builtin_amdgcn_s_setprio(1);
      #pragma unroll
      for (int nb = 0; nb < 4; ++nb) {
        const int rk = nb * 16 + c;
        const int swz = (rk & 7) << 4;
        #pragma unroll
        for (int ks = 0; ks < 4; ++ks) {
          bf16x8 kf = *(const bf16x8*)((const char*)K_ + rk * 256 + ((ks * 64 + g * 16) ^ swz));
          sa[0][nb] = __builtin_amdgcn_mfma_f32_16x16x32_bf16(kf, qf[0][ks], sa[0][nb], 0, 0, 0);
          sa[1][nb] = __builtin_amdgcn_mfma_f32_16x16x32_bf16(kf, qf[1][ks], sa[1][nb], 0, 0, 0);
        }
      }
      __builtin_amdgcn_s_setprio(0);
      const bool diag = (kv0 + 63 > q0w);
      #pragma unroll
      for (int m = 0; m < 2; ++m) {
        const int q = q0w + m * 16 + c;
        float p[4][4];
        float rs = 0.f;
        if (diag) {
          #pragma unroll
          for (int nb = 0; nb < 4; ++nb)
            #pragma unroll
            for (int r = 0; r < 4; ++r) {
              float s = (kv0 + nb * 16 + g * 4 + r > q) ? -1e30f : sa[m][nb][r];
              p[nb][r] = exp2_hw(s);
              rs += p[nb][r];
            }
        } else {
          #pragma unroll
          for (int nb = 0; nb < 4; ++nb)
            #pragma unroll
            for (int r = 0; r < 4; ++r) {
              p[nb][r] = exp2_hw(sa[m][nb][r]);
              rs += p[nb][r];
            }
        }
        lsum[m] += rs;
        const int rowp = m * 16 + c;
        const int swzp = (rowp & 7) << 4;
        #pragma unroll
        for (int nb = 0; nb < 4; ++nb)
          #pragma unroll
          for (int i2 = 0; i2 < 2; ++i2) {
            u32 w = cvtpk_bf16(p[nb][2 * i2], p[nb][2 * i2 + 1]);
            *(u32*)((char*)Pl[wave] + rowp * 128 + (((nb * 16 + g * 4 + 2 * i2) * 2) ^ swzp)) = w;
          }
      }
      asm volatile("s_waitcnt lgkmcnt(0)" ::: "memory");
      __builtin_amdgcn_sched_barrier(0);
      bf16x8 pf[2][2];
      #pragma unroll
      for (int m = 0; m < 2; ++m)
        #pragma unroll
        for (int c2 = 0; c2 < 2; ++c2) {
          int rowp = m * 16 + c;
          pf[m][c2] = *(const bf16x8*)((const char*)Pl[wave] + rowp * 128 +
                                       ((c2 * 64 + g * 16) ^ ((rowp & 7) << 4)));
        }
      __builtin_amdgcn_s_setprio(1);
      #pragma unroll
      for (int nf = 0; nf < 8; ++nf) {
        const int rv = nf * 16 + c;
        const int swzv = (rv & 7) << 4;
        #pragma unroll
        for (int c2 = 0; c2 < 2; ++c2) {
          bf16x8 vf = *(const bf16x8*)((const char*)V_ + rv * 128 + ((c2 * 64 + g * 16) ^ swzv));
          acc[0][nf] = __builtin_amdgcn_mfma_f32_16x16x32_bf16(pf[0][c2], vf, acc[0][nf], 0, 0, 0);
          acc[1][nf] = __builtin_amdgcn_mfma_f32_16x16x32_bf16(pf[1][c2], vf, acc[1][nf], 0, 0, 0);
        }
      }
      __builtin_amdgcn_s_setprio(0);
    }
    __syncthreads();
  }

  #pragma unroll
  for (int m = 0; m < 2; ++m) {
    lsum[m] += __shfl_xor(lsum[m], 16, 64);
    lsum[m] += __shfl_xor(lsum[m], 32, 64);
  }

  unsigned short* Op = O + (size_t)b * SS * DD + (size_t)h * DHH;
  #pragma unroll
  for (int m = 0; m < 2; ++m) {
    float inv = 1.0f / lsum[m];
    float invr[4];
    #pragma unroll
    for (int r = 0; r < 4; ++r)
      invr[r] = __shfl(inv, 20 * g + r, 64);
    #pragma unroll
    for (int nf = 0; nf < 8; ++nf)
      #pragma unroll
      for (int r = 0; r < 4; ++r) {
        int q = q0w + m * 16 + g * 4 + r;
        Op[(size_t)q * DD + nf * 16 + c] = f2bf(acc[m][nf][r] * invr[r]);
      }
  }
}

extern "C" void kernel_launch(void* const* d_in, const int* in_sizes, int n_in,
                              void* d_out, int out_size, void* d_ws, size_t ws_size,
                              hipStream_t stream) {
  const float* x     = (const float*)d_in[0];
  const float* Wqkv  = (const float*)d_in[1];
  const float* bqkv  = (const float*)d_in[2];
  const float* Wproj = (const float*)d_in[3];
  const float* bproj = (const float*)d_in[4];
  float* out = (float*)d_out;

  char* ws = (char*)d_ws;
  unsigned short* xb  = (unsigned short*)ws; ws += (size_t)MM * DD * 2;
  unsigned short* w1t = (unsigned short*)ws; ws += (size_t)NN1 * DD * 2;
  unsigned short* w2t = (unsigned short*)ws; ws += (size_t)DD * DD * 2;
  unsigned short* Qb  = (unsigned short*)ws; ws += (size_t)BB * HH * SS * DHH * 2;
  unsigned short* Kb  = (unsigned short*)ws; ws += (size_t)BB * HH * SS * DHH * 2;
  unsigned short* Vt  = (unsigned short*)ws; ws += (size_t)BB * HH * SS * DHH * 2;
  unsigned short* Ob  = (unsigned short*)ws; ws += (size_t)MM * DD * 2;

  k_prep<<<dim3(16384), 256, 0, stream>>>(x, xb, Wqkv, w1t, Wproj, w2t);
  k_gemm1<<<dim3(512), 512, 0, stream>>>(xb, w1t, bqkv, Qb, Kb, Vt);
  k_attn<<<dim3(512), 256, 0, stream>>>(Qb, Kb, Vt, Ob);
  k_gemm2<<<dim3(DD / 128, MM / 256), 512, 0, stream>>>(Ob, w2t, bproj, out);
}

// Round 24
// 226.232 us; speedup vs baseline: 2.3790x; 1.0067x over previous
//
#include <hip/hip_runtime.h>
#include <hip/hip_bf16.h>

#define BB 2
#define SS 2048
#define DD 2048
#define HH 16
#define DHH 128
#define MM 4096      // B*S
#define NN1 6144     // 3*D
#define NTILES (DD / 64)   // 32 K-tiles of 64

typedef __attribute__((ext_vector_type(8))) short bf16x8;
typedef __attribute__((ext_vector_type(4))) float f32x4;
typedef unsigned int u32;

static __device__ __forceinline__ float exp2_hw(float x) {
  return __builtin_amdgcn_exp2f(x);   // v_exp_f32
}

static __device__ __forceinline__ unsigned short f2bf(float f) {
  union { float f; u32 u; } v; v.f = f;
  return (unsigned short)((v.u + 0x7FFFu + ((v.u >> 16) & 1u)) >> 16);
}

static __device__ __forceinline__ u32 cvtpk_bf16(float lo, float hi) {
  u32 r;
  asm("v_cvt_pk_bf16_f32 %0, %1, %2" : "=v"(r) : "v"(lo), "v"(hi));
  return r;
}

static __device__ __forceinline__ void gload_lds16(const void* g, void* l) {
  __builtin_amdgcn_global_load_lds((const __attribute__((address_space(1))) u32*)g,
                                   (__attribute__((address_space(3))) u32*)l, 16, 0, 0);
}

// ---- fused prep (r23-proven): cvt x->bf16 + transpose Wqkv + transpose Wproj ----
__global__ __launch_bounds__(256) void k_prep(const float* __restrict__ x,
                                              unsigned short* __restrict__ xb,
                                              const float* __restrict__ Wqkv,
                                              unsigned short* __restrict__ w1t,
                                              const float* __restrict__ Wproj,
                                              unsigned short* __restrict__ w2t) {
  const int bid = blockIdx.x, tid = threadIdx.x;
  if (bid < 8192) {                      // ---- cvt: x (f32) -> xb (bf16) ----
    int i = bid * 256 + tid;
    float4 v = ((const float4*)x)[i];
    ushort4 o;
    o.x = f2bf(v.x); o.y = f2bf(v.y); o.z = f2bf(v.z); o.w = f2bf(v.w);
    ((ushort4*)xb)[i] = o;
    return;                              // block-uniform exit (no sync hazard)
  }
  __shared__ float t[64][33];
  const float* in; unsigned short* out;
  int R, C, bx, by;
  if (bid < 14336) {                     // ---- Wqkv [DD][NN1] -> w1t [NN1][DD] ----
    int idx = bid - 8192;                // 192 x 32 tiles
    in = Wqkv; out = w1t; R = DD; C = NN1;
    bx = (idx % 192) * 32; by = (idx / 192) * 64;
  } else {                               // ---- Wproj [DD][DD] -> w2t [DD][DD] ----
    int idx = bid - 14336;               // 64 x 32 tiles
    in = Wproj; out = w2t; R = DD; C = DD;
    bx = (idx % 64) * 32; by = (idx / 64) * 64;
  }
  const int tx = tid & 31, ty = tid >> 5;
  #pragma unroll
  for (int rr = 0; rr < 8; ++rr)
    t[ty + 8 * rr][tx] = in[(size_t)(by + ty + 8 * rr) * C + bx + tx];
  __syncthreads();
  #pragma unroll
  for (int ii = 0; ii < 4; ++ii) {
    int i = ty + 8 * ii;
    ushort2 w;
    w.x = f2bf(t[2 * tx][i]);
    w.y = f2bf(t[2 * tx + 1][i]);
    *(ushort2*)&out[(size_t)(bx + i) * R + by + 2 * tx] = w;
  }
}

// ======= GEMM1 core (r13/r17-proven): 256x192 / BK=64 / 2Mx4N waves / dbuf 112KB =======
__device__ __forceinline__ void gemm_core192(const char* __restrict__ Ag,
                                             const char* __restrict__ Bg,
                                             char* lds, f32x4 acc[8][3]) {
  const int tid = threadIdx.x;
  const int wave = tid >> 6, lane = tid & 63;
  const int g = lane >> 4, c = lane & 15;
  const int wm = wave >> 2, wn = wave & 3;

  auto stage = [&](int buf, int kt) {
    char* base = lds + buf * 57344;
    #pragma unroll
    for (int q = 0; q < 4; ++q) {          // A: 4 loads/thread
      int off = q * 8192 + tid * 16;
      int row = off >> 7, cb = off & 127;
      gload_lds16(Ag + (size_t)row * 4096 + kt * 128 + (cb ^ ((row & 7) << 4)),
                  base + q * 8192 + wave * 1024);
    }
    #pragma unroll
    for (int q = 0; q < 3; ++q) {          // B: 3 loads/thread
      int off = q * 8192 + tid * 16;
      int row = off >> 7, cb = off & 127;
      gload_lds16(Bg + (size_t)row * 4096 + kt * 128 + (cb ^ ((row & 7) << 4)),
                  base + 32768 + q * 8192 + wave * 1024);
    }
  };

  stage(0, 0);
  asm volatile("s_waitcnt vmcnt(0)" ::: "memory");
  __builtin_amdgcn_sched_barrier(0);
  __builtin_amdgcn_s_barrier();

  for (int t = 0; t < NTILES; ++t) {
    const char* Ab = lds + (t & 1) * 57344;
    const char* Bb = Ab + 32768;
    bf16x8 af[8][2], bfv[3][2];
    #pragma unroll
    for (int i = 0; i < 8; ++i) {
      int row = wm * 128 + i * 16 + c;
      af[i][0] = *(const bf16x8*)(Ab + row * 128 + ((g * 16) ^ ((row & 7) << 4)));
    }
    #pragma unroll
    for (int j = 0; j < 3; ++j) {
      int row = wn * 48 + j * 16 + c;
      bfv[j][0] = *(const bf16x8*)(Bb + row * 128 + ((g * 16) ^ ((row & 7) << 4)));
    }
    __builtin_amdgcn_sched_barrier(0);
    #pragma unroll
    for (int i = 0; i < 8; ++i) {
      int row = wm * 128 + i * 16 + c;
      af[i][1] = *(const bf16x8*)(Ab + row * 128 + ((64 + g * 16) ^ ((row & 7) << 4)));
    }
    #pragma unroll
    for (int j = 0; j < 3; ++j) {
      int row = wn * 48 + j * 16 + c;
      bfv[j][1] = *(const bf16x8*)(Bb + row * 128 + ((64 + g * 16) ^ ((row & 7) << 4)));
    }
    if (t + 1 < NTILES) stage((t + 1) & 1, t + 1);
    asm volatile("s_waitcnt lgkmcnt(11)" ::: "memory");
    __builtin_amdgcn_sched_barrier(0);
    __builtin_amdgcn_s_setprio(1);
    #pragma unroll
    for (int i = 0; i < 8; ++i)
      #pragma unroll
      for (int j = 0; j < 3; ++j)
        acc[i][j] = __builtin_amdgcn_mfma_f32_16x16x32_bf16(af[i][0], bfv[j][0], acc[i][j], 0, 0, 0);
    __builtin_amdgcn_s_setprio(0);
    asm volatile("s_waitcnt lgkmcnt(0)" ::: "memory");
    __builtin_amdgcn_sched_barrier(0);
    __builtin_amdgcn_s_setprio(1);
    #pragma unroll
    for (int i = 0; i < 8; ++i)
      #pragma unroll
      for (int j = 0; j < 3; ++j)
        acc[i][j] = __builtin_amdgcn_mfma_f32_16x16x32_bf16(af[i][1], bfv[j][1], acc[i][j], 0, 0, 0);
    __builtin_amdgcn_s_setprio(0);
    if (t < NTILES - 1) {
      asm volatile("s_waitcnt vmcnt(0)" ::: "memory");
      __builtin_amdgcn_sched_barrier(0);
      __builtin_amdgcn_s_barrier();
    }
  }
}

// ========= r10-proven gemm2 core: 256x128 / BK=64 / split-lgkm / 144KB =========
__device__ __forceinline__ void gemm_core(const char* __restrict__ Ag,
                                          const char* __restrict__ Bg,
                                          char* Alds, char* Blds,
                                          f32x4 acc[4][4]) {
  const int tid = threadIdx.x;
  const int wave = tid >> 6, lane = tid & 63;
  const int g = lane >> 4, c = lane & 15;
  const int wm = wave >> 1, wn = wave & 1;

  auto stageA = [&](int buf, int kt) {
    #pragma unroll
    for (int q = 0; q < 4; ++q) {
      int off = q * 8192 + wave * 1024 + (lane << 4);
      int row = off >> 7, cb = off & 127;
      gload_lds16(Ag + (size_t)row * 4096 + kt * 128 + (cb ^ ((row & 7) << 4)),
                  Alds + buf * 32768 + q * 8192 + wave * 1024);
    }
  };
  auto stageB = [&](int buf, int kt) {
    #pragma unroll
    for (int q = 0; q < 2; ++q) {
      int off = q * 8192 + wave * 1024 + (lane << 4);
      int row = off >> 7, cb = off & 127;
      gload_lds16(Bg + (size_t)row * 4096 + kt * 128 + (cb ^ ((row & 7) << 4)),
                  Blds + buf * 16384 + q * 8192 + wave * 1024);
    }
  };

  stageA(0, 0); stageB(0, 0);
  stageA(1, 1); stageB(1, 1);
  asm volatile("s_waitcnt vmcnt(6)" ::: "memory");
  __builtin_amdgcn_sched_barrier(0);
  __builtin_amdgcn_s_barrier();

  for (int t = 0; t < NTILES; ++t) {
    const int buf = t % 3;
    const char* Ab = Alds + buf * 32768;
    const char* Bb = Blds + buf * 16384;
    bf16x8 af[4][2], bfv[4][2];
    #pragma unroll
    for (int i = 0; i < 4; ++i) {
      int row = wm * 64 + i * 16 + c;
      af[i][0] = *(const bf16x8*)(Ab + row * 128 + ((g * 16) ^ ((row & 7) << 4)));
    }
    #pragma unroll
    for (int j = 0; j < 4; ++j) {
      int row = wn * 64 + j * 16 + c;
      bfv[j][0] = *(const bf16x8*)(Bb + row * 128 + ((g * 16) ^ ((row & 7) << 4)));
    }
    __builtin_amdgcn_sched_barrier(0);
    #pragma unroll
    for (int i = 0; i < 4; ++i) {
      int row = wm * 64 + i * 16 + c;
      af[i][1] = *(const bf16x8*)(Ab + row * 128 + ((64 + g * 16) ^ ((row & 7) << 4)));
    }
    #pragma unroll
    for (int j = 0; j < 4; ++j) {
      int row = wn * 64 + j * 16 + c;
      bfv[j][1] = *(const bf16x8*)(Bb + row * 128 + ((64 + g * 16) ^ ((row & 7) << 4)));
    }
    if (t + 2 < NTILES) {
      int nb = buf + 2; if (nb >= 3) nb -= 3;
      stageA(nb, t + 2);
      stageB(nb, t + 2);
    }
    asm volatile("s_waitcnt lgkmcnt(8)" ::: "memory");
    __builtin_amdgcn_sched_barrier(0);
    __builtin_amdgcn_s_setprio(1);
    #pragma unroll
    for (int i = 0; i < 4; ++i)
      #pragma unroll
      for (int j = 0; j < 4; ++j)
        acc[i][j] = __builtin_amdgcn_mfma_f32_16x16x32_bf16(af[i][0], bfv[j][0], acc[i][j], 0, 0, 0);
    __builtin_amdgcn_s_setprio(0);
    asm volatile("s_waitcnt lgkmcnt(0)" ::: "memory");
    __builtin_amdgcn_sched_barrier(0);
    __builtin_amdgcn_s_setprio(1);
    #pragma unroll
    for (int i = 0; i < 4; ++i)
      #pragma unroll
      for (int j = 0; j < 4; ++j)
        acc[i][j] = __builtin_amdgcn_mfma_f32_16x16x32_bf16(af[i][1], bfv[j][1], acc[i][j], 0, 0, 0);
    __builtin_amdgcn_s_setprio(0);
    if (t < NTILES - 1) {
      if (t + 2 < NTILES) { asm volatile("s_waitcnt vmcnt(6)" ::: "memory"); }
      else                { asm volatile("s_waitcnt vmcnt(0)" ::: "memory"); }
      __builtin_amdgcn_sched_barrier(0);
      __builtin_amdgcn_s_barrier();
    }
  }
}

// ---- GEMM1: x[M][K] * Wqkv^T[N][K] + bqkv -> scatter Q/K/Vt (Q pre-scaled) ----
__global__ __launch_bounds__(512, 1) void k_gemm1(const unsigned short* __restrict__ A,
                                                  const unsigned short* __restrict__ Bt,
                                                  const float* __restrict__ bias,
                                                  unsigned short* __restrict__ Qb,
                                                  unsigned short* __restrict__ Kb,
                                                  unsigned short* __restrict__ Vt) {
  __shared__ __align__(16) char lds[114688];
  const int x = blockIdx.x & 7, k = blockIdx.x >> 3;
  const int mt = (x & 1) * 8 + (k & 7), nt = (x >> 1) * 8 + (k >> 3);
  const int m0 = mt * 256, n0 = nt * 192;
  f32x4 acc[8][3] = {};
  gemm_core192((const char*)A + (size_t)m0 * 4096,
               (const char*)Bt + (size_t)n0 * 4096,
               lds, acc);
  const int lane = threadIdx.x & 63, wave = threadIdx.x >> 6;
  const int g = lane >> 4, c = lane & 15;
  const int wm = wave >> 2, wn = wave & 3;
  const float qsc = 0.12751879523263566f;  // (1/sqrt(128)) * log2(e): folded into Q
  #pragma unroll
  for (int i = 0; i < 8; ++i) {
    int rowb = m0 + wm * 128 + i * 16 + g * 4;
    int bb = rowb >> 11, s = rowb & 2047;
    #pragma unroll
    for (int j = 0; j < 3; ++j) {
      int gcol = n0 + wn * 48 + j * 16 + c;
      int which = gcol >> 11;
      int head = (gcol >> 7) & 15, dh = gcol & 127;
      float bv = bias[gcol];
      if (which == 2) {
        ushort4 p;
        p.x = f2bf(acc[i][j][0] + bv);
        p.y = f2bf(acc[i][j][1] + bv);
        p.z = f2bf(acc[i][j][2] + bv);
        p.w = f2bf(acc[i][j][3] + bv);
        *(ushort4*)(Vt + ((size_t)(bb * HH + head) * DHH + dh) * SS + s) = p;
      } else {
        float v0 = acc[i][j][0] + bv, v1 = acc[i][j][1] + bv;
        float v2 = acc[i][j][2] + bv, v3 = acc[i][j][3] + bv;
        if (which == 0) { v0 *= qsc; v1 *= qsc; v2 *= qsc; v3 *= qsc; }
        unsigned short* dst = (which == 0 ? Qb : Kb) + ((size_t)(bb * HH + head) * SS + s) * DHH + dh;
        dst[0]       = f2bf(v0);
        dst[DHH]     = f2bf(v1);
        dst[2 * DHH] = f2bf(v2);
        dst[3 * DHH] = f2bf(v3);
      }
    }
  }
}

// ---- GEMM2: O[M][D] * Wproj^T[D][D] + bproj -> f32 out (r10 core, XCD-rect grid) ----
__global__ __launch_bounds__(512, 1) void k_gemm2(const unsigned short* __restrict__ A,
                                                  const unsigned short* __restrict__ Bt,
                                                  const float* __restrict__ bias,
                                                  float* __restrict__ out) {
  __shared__ __align__(16) char lds[147456];
  // 256 blocks; per XCD a 4m x 8n rect: B-panel 4MB L2-resident per XCD
  const int x = blockIdx.x & 7, k = blockIdx.x >> 3;
  const int mt = (x & 3) * 4 + (k & 3), nt = (x >> 2) * 8 + (k >> 2);
  const int m0 = mt * 256, n0 = nt * 128;
  f32x4 acc[4][4] = {};
  gemm_core((const char*)A + (size_t)m0 * 4096,
            (const char*)Bt + (size_t)n0 * 4096,
            lds, lds + 98304, acc);
  const int lane = threadIdx.x & 63, wave = threadIdx.x >> 6;
  const int g = lane >> 4, c = lane & 15;
  const int wm = wave >> 1, wn = wave & 1;
  #pragma unroll
  for (int i = 0; i < 4; ++i) {
    int rowb = m0 + wm * 64 + i * 16 + g * 4;
    #pragma unroll
    for (int j = 0; j < 4; ++j) {
      int gcol = n0 + wn * 64 + j * 16 + c;
      float bv = bias[gcol];
      #pragma unroll
      for (int r = 0; r < 4; ++r)
        out[(size_t)(rowb + r) * DD + gcol] = acc[i][j][r] + bv;
    }
  }
}

// ---- flash attention v7 (r17-proven): XCD-local bh mapping, no-max softmax,
//      deferred lsum reduction, cvt_pk P-packing ----
__global__ __launch_bounds__(256, 2) void k_attn(const unsigned short* __restrict__ Qb,
                                                 const unsigned short* __restrict__ Kb,
                                                 const unsigned short* __restrict__ Vt,
                                                 unsigned short* __restrict__ O) {
  __shared__ __align__(16) unsigned short Kt[2][64 * 128];
  __shared__ __align__(16) unsigned short Vs[2][128 * 64];
  __shared__ __align__(16) unsigned short Pl[4][32 * 64];
  const int L = blockIdx.x;
  const int xcd = L & 7, slot = L >> 3;
  const int bh = (xcd << 2) | (slot >> 4);
  const int sloc = slot & 15;
  const int qtl = (slot & 32) ? (15 - sloc) : sloc;
  const int b = bh >> 4, h = bh & 15;
  const int tid = threadIdx.x, wave = tid >> 6, lane = tid & 63;
  const int g = lane >> 4, c = lane & 15;
  const int q0w = qtl * 128 + wave * 32;
  const unsigned short* Qp = Qb + (size_t)bh * SS * DHH;
  const unsigned short* Kp = Kb + (size_t)bh * SS * DHH;
  const unsigned short* Vp = Vt + (size_t)bh * DHH * SS;

  bf16x8 qf[2][4];
  #pragma unroll
  for (int m = 0; m < 2; ++m)
    #pragma unroll
    for (int ks = 0; ks < 4; ++ks)
      qf[m][ks] = *(const bf16x8*)(Qp + (size_t)(q0w + m * 16 + c) * DHH + ks * 32 + g * 8);

  f32x4 acc[2][8] = {};
  float lsum[2] = {0.f, 0.f};

  auto stage = [&](int buf, int kv0) {
    #pragma unroll
    for (int r = 0; r < 4; ++r) {
      int base = r * 4096 + wave * 1024;
      int off = base + (lane << 4);
      { int row = off >> 8; int cb = (off & 255) ^ ((row & 7) << 4);
        gload_lds16((const char*)Kp + (size_t)(kv0 + row) * 256 + cb,
                    (char*)Kt[buf] + base); }
      { int row = off >> 7; int cb = (off & 127) ^ ((row & 7) << 4);
        gload_lds16((const char*)Vp + (size_t)row * (SS * 2) + (size_t)kv0 * 2 + cb,
                    (char*)Vs[buf] + base); }
    }
  };

  const int ntiles = 2 * qtl + 2;
  stage(0, 0);
  __syncthreads();

  for (int t = 0; t < ntiles; ++t) {
    const int cur = t & 1;
    const int kv0 = t * 64;
    if (t + 1 < ntiles) stage(cur ^ 1, kv0 + 64);
    if (kv0 <= q0w + 31) {
      const unsigned short* K_ = Kt[cur];
      const unsigned short* V_ = Vs[cur];
      f32x4 sa[2][4] = {};
      __builtin_amdgcn_s_setprio(1);
      #pragma unroll
      for (int nb = 0; nb < 4; ++nb) {
        const int rk = nb * 16 + c;
        const int swz = (rk & 7) << 4;
        #pragma unroll
        for (int ks = 0; ks < 4; ++ks) {
          bf16x8 kf = *(const bf16x8*)((const char*)K_ + rk * 256 + ((ks * 64 + g * 16) ^ swz));
          sa[0][nb] = __builtin_amdgcn_mfma_f32_16x16x32_bf16(kf, qf[0][ks], sa[0][nb], 0, 0, 0);
          sa[1][nb] = __builtin_amdgcn_mfma_f32_16x16x32_bf16(kf, qf[1][ks], sa[1][nb], 0, 0, 0);
        }
      }
      __builtin_amdgcn_s_setprio(0);
      const bool diag = (kv0 + 63 > q0w);
      #pragma unroll
      for (int m = 0; m < 2; ++m) {
        const int q = q0w + m * 16 + c;
        float p[4][4];
        float rs = 0.f;
        if (diag) {
          #pragma unroll
          for (int nb = 0; nb < 4; ++nb)
            #pragma unroll
            for (int r = 0; r < 4; ++r) {
              float s = (kv0 + nb * 16 + g * 4 + r > q) ? -1e30f : sa[m][nb][r];
              p[nb][r] = exp2_hw(s);
              rs += p[nb][r];
            }
        } else {
          #pragma unroll
          for (int nb = 0; nb < 4; ++nb)
            #pragma unroll
            for (int r = 0; r < 4; ++r) {
              p[nb][r] = exp2_hw(sa[m][nb][r]);
              rs += p[nb][r];
            }
        }
        lsum[m] += rs;
        const int rowp = m * 16 + c;
        const int swzp = (rowp & 7) << 4;
        #pragma unroll
        for (int nb = 0; nb < 4; ++nb)
          #pragma unroll
          for (int i2 = 0; i2 < 2; ++i2) {
            u32 w = cvtpk_bf16(p[nb][2 * i2], p[nb][2 * i2 + 1]);
            *(u32*)((char*)Pl[wave] + rowp * 128 + (((nb * 16 + g * 4 + 2 * i2) * 2) ^ swzp)) = w;
          }
      }
      asm volatile("s_waitcnt lgkmcnt(0)" ::: "memory");
      __builtin_amdgcn_sched_barrier(0);
      bf16x8 pf[2][2];
      #pragma unroll
      for (int m = 0; m < 2; ++m)
        #pragma unroll
        for (int c2 = 0; c2 < 2; ++c2) {
          int rowp = m * 16 + c;
          pf[m][c2] = *(const bf16x8*)((const char*)Pl[wave] + rowp * 128 +
                                       ((c2 * 64 + g * 16) ^ ((rowp & 7) << 4)));
        }
      __builtin_amdgcn_s_setprio(1);
      #pragma unroll
      for (int nf = 0; nf < 8; ++nf) {
        const int rv = nf * 16 + c;
        const int swzv = (rv & 7) << 4;
        #pragma unroll
        for (int c2 = 0; c2 < 2; ++c2) {
          bf16x8 vf = *(const bf16x8*)((const char*)V_ + rv * 128 + ((c2 * 64 + g * 16) ^ swzv));
          acc[0][nf] = __builtin_amdgcn_mfma_f32_16x16x32_bf16(pf[0][c2], vf, acc[0][nf], 0, 0, 0);
          acc[1][nf] = __builtin_amdgcn_mfma_f32_16x16x32_bf16(pf[1][c2], vf, acc[1][nf], 0, 0, 0);
        }
      }
      __builtin_amdgcn_s_setprio(0);
    }
    __syncthreads();
  }

  #pragma unroll
  for (int m = 0; m < 2; ++m) {
    lsum[m] += __shfl_xor(lsum[m], 16, 64);
    lsum[m] += __shfl_xor(lsum[m], 32, 64);
  }

  unsigned short* Op = O + (size_t)b * SS * DD + (size_t)h * DHH;
  #pragma unroll
  for (int m = 0; m < 2; ++m) {
    float inv = 1.0f / lsum[m];
    float invr[4];
    #pragma unroll
    for (int r = 0; r < 4; ++r)
      invr[r] = __shfl(inv, 20 * g + r, 64);
    #pragma unroll
    for (int nf = 0; nf < 8; ++nf)
      #pragma unroll
      for (int r = 0; r < 4; ++r) {
        int q = q0w + m * 16 + g * 4 + r;
        Op[(size_t)q * DD + nf * 16 + c] = f2bf(acc[m][nf][r] * invr[r]);
      }
  }
}

extern "C" void kernel_launch(void* const* d_in, const int* in_sizes, int n_in,
                              void* d_out, int out_size, void* d_ws, size_t ws_size,
                              hipStream_t stream) {
  const float* x     = (const float*)d_in[0];
  const float* Wqkv  = (const float*)d_in[1];
  const float* bqkv  = (const float*)d_in[2];
  const float* Wproj = (const float*)d_in[3];
  const float* bproj = (const float*)d_in[4];
  float* out = (float*)d_out;

  char* ws = (char*)d_ws;
  unsigned short* xb  = (unsigned short*)ws; ws += (size_t)MM * DD * 2;
  unsigned short* w1t = (unsigned short*)ws; ws += (size_t)NN1 * DD * 2;
  unsigned short* w2t = (unsigned short*)ws; ws += (size_t)DD * DD * 2;
  unsigned short* Qb  = (unsigned short*)ws; ws += (size_t)BB * HH * SS * DHH * 2;
  unsigned short* Kb  = (unsigned short*)ws; ws += (size_t)BB * HH * SS * DHH * 2;
  unsigned short* Vt  = (unsigned short*)ws; ws += (size_t)BB * HH * SS * DHH * 2;
  unsigned short* Ob  = (unsigned short*)ws; ws += (size_t)MM * DD * 2;

  k_prep<<<dim3(16384), 256, 0, stream>>>(x, xb, Wqkv, w1t, Wproj, w2t);
  k_gemm1<<<dim3(512), 512, 0, stream>>>(xb, w1t, bqkv, Qb, Kb, Vt);
  k_attn<<<dim3(512), 256, 0, stream>>>(Qb, Kb, Vt, Ob);
  k_gemm2<<<dim3(256), 512, 0, stream>>>(Ob, w2t, bproj, out);
}